// Round 1
// baseline (470.826 us; speedup 1.0000x reference)
//
#include <hip/hip_runtime.h>

// EpochedFutureFill == causal FIR conv, computed as FFT conv (n_fft = 131072).
// Four-step FFT: N = N1(512) x N2(256), transpose-free (permuted spectrum,
// filter spectrum computed with same permutation, inverse undoes it).
// Batch trick: rows (2b, 2b+1) packed as re/im of one complex row (filter real).

#define N_FFT 131072
#define N1    512
#define N2    256
#define T_LEN 65536
#define CB    128          // complex batch rows (256 real rows / 2)
#define PI_F  3.14159265358979323846f

__device__ inline int brev9(int x) { return (int)(__brev((unsigned)x) >> 23); }
__device__ inline int brev8(int x) { return (int)(__brev((unsigned)x) >> 24); }

// ---------------------------------------------------------------------------
// Forward column FFTs (length 512, stride 256) + twiddle W_N^{n2*k1}.
// Input: real row(s) (re, optional im), length 65536, zero-padded to 131072.
// Output: dst[row][k1*256 + n2]  (column-transformed, twiddled)
// ---------------------------------------------------------------------------
__global__ __launch_bounds__(256) void fwd_cols(
    const float* __restrict__ re_base, const float* __restrict__ im_base,
    long long row_stride, float2* __restrict__ dst)
{
    const int tile = blockIdx.x;          // 16 tiles x 16 columns
    const int row  = blockIdx.y;
    const int tid  = threadIdx.x;
    __shared__ float sre[N1 * 16];
    __shared__ float sim[N1 * 16];

    const float* rp = re_base + (long long)row * row_stride;
    const float* ip = im_base ? (im_base + (long long)row * row_stride) : nullptr;
    const int n2base = tile * 16;

    // load (bit-reverse n1 on LDS store); n1 >= 256 -> zero pad
    for (int i = 0; i < 32; i++) {
        int idx = tid + i * 256;
        int n1  = idx >> 4;
        int cc  = idx & 15;
        float vr = 0.f, vi = 0.f;
        if (n1 < 256) {
            int n = n1 * N2 + n2base + cc;
            vr = rp[n];
            vi = ip ? ip[n] : 0.f;
        }
        int p = brev9(n1);
        sre[p * 16 + cc] = vr;
        sim[p * 16 + cc] = vi;
    }
    __syncthreads();

    const int c = tid & 15;
    const int r = tid >> 4;               // 0..15
    for (int s = 0; s < 9; s++) {         // radix-2 DIT, forward (-angle)
        int h = 1 << s;
        for (int jj = 0; jj < 16; jj++) {
            int beta = jj * 16 + r;       // 0..255
            int j  = beta & (h - 1);
            int i1 = ((beta >> s) << (s + 1)) | j;
            int i2 = i1 + h;
            float ang = -PI_F * (float)j / (float)h;
            float wr = __cosf(ang), wi = __sinf(ang);
            float ur = sre[i1 * 16 + c], ui = sim[i1 * 16 + c];
            float vr = sre[i2 * 16 + c], vi = sim[i2 * 16 + c];
            float tr = vr * wr - vi * wi;
            float ti = vr * wi + vi * wr;
            sre[i1 * 16 + c] = ur + tr; sim[i1 * 16 + c] = ui + ti;
            sre[i2 * 16 + c] = ur - tr; sim[i2 * 16 + c] = ui - ti;
        }
        __syncthreads();
    }

    // twiddle W_N^{n2*k1}, store natural k1
    float2* drow = dst + (size_t)row * N_FFT;
    for (int i = 0; i < 32; i++) {
        int idx = tid + i * 256;
        int k1 = idx >> 4;
        int cc = idx & 15;
        int n2 = n2base + cc;
        float ang = -2.f * PI_F * (float)(n2 * k1) / (float)N_FFT;
        float wr = __cosf(ang), wi = __sinf(ang);
        float ar = sre[k1 * 16 + cc], ai = sim[k1 * 16 + cc];
        drow[(size_t)k1 * N2 + n2] = make_float2(ar * wr - ai * wi, ar * wi + ai * wr);
    }
}

// ---------------------------------------------------------------------------
// Filter spectrum row FFTs (len 256, contiguous), natural order in/out.
// (bit-reverse on load, DIT forward)
// ---------------------------------------------------------------------------
__global__ __launch_bounds__(256) void fwd_rows_g(float2* __restrict__ G)
{
    const int tid = threadIdx.x;
    const long long rbase = (long long)blockIdx.x * 8;
    __shared__ float sre[8 * 256], sim[8 * 256];
    float2* gptr = G + rbase * N2;

    int pb = brev8(tid);
    for (int i = 0; i < 8; i++) {
        float2 v = gptr[i * 256 + tid];
        sre[i * 256 + pb] = v.x;
        sim[i * 256 + pb] = v.y;
    }
    __syncthreads();
    const int rl = tid >> 5, rr = tid & 31;
    for (int s = 0; s < 8; s++) {
        int h = 1 << s;
        int base = rl * 256;
        for (int jj = 0; jj < 4; jj++) {
            int beta = jj * 32 + rr;
            int j  = beta & (h - 1);
            int i1 = ((beta >> s) << (s + 1)) | j;
            int i2 = i1 + h;
            float ang = -PI_F * (float)j / (float)h;
            float wr = __cosf(ang), wi = __sinf(ang);
            float ur = sre[base + i1], ui = sim[base + i1];
            float vr = sre[base + i2], vi = sim[base + i2];
            float tr = vr * wr - vi * wi;
            float ti = vr * wi + vi * wr;
            sre[base + i1] = ur + tr; sim[base + i1] = ui + ti;
            sre[base + i2] = ur - tr; sim[base + i2] = ui - ti;
        }
        __syncthreads();
    }
    for (int i = 0; i < 8; i++)
        gptr[i * 256 + tid] = make_float2(sre[i * 256 + tid], sim[i * 256 + tid]);
}

// ---------------------------------------------------------------------------
// Fused: forward row FFT (DIF, natural->brev) -> x G (at brev pos) ->
// inverse row FFT (DIT, brev->natural) -> conj twiddle W_N^{-n2*k1}. In-place.
// ---------------------------------------------------------------------------
__global__ __launch_bounds__(256) void mid_rows(
    float2* __restrict__ buf, const float2* __restrict__ G)
{
    const int tid = threadIdx.x;
    const long long rbase = (long long)blockIdx.x * 8;
    __shared__ float sre[8 * 256], sim[8 * 256];
    float2* gptr = buf + rbase * N2;

    for (int i = 0; i < 8; i++) {
        float2 v = gptr[i * 256 + tid];
        sre[i * 256 + tid] = v.x;
        sim[i * 256 + tid] = v.y;
    }
    __syncthreads();

    const int rl = tid >> 5, rr = tid & 31;
    // forward DIF: h = 128 .. 1, natural in -> bit-reversed out
    for (int s = 7; s >= 0; s--) {
        int h = 1 << s;
        int base = rl * 256;
        for (int jj = 0; jj < 4; jj++) {
            int beta = jj * 32 + rr;
            int j  = beta & (h - 1);
            int i1 = ((beta >> s) << (s + 1)) | j;
            int i2 = i1 + h;
            float ang = -PI_F * (float)j / (float)h;
            float wr = __cosf(ang), wi = __sinf(ang);
            float ur = sre[base + i1], ui = sim[base + i1];
            float vr = sre[base + i2], vi = sim[base + i2];
            sre[base + i1] = ur + vr; sim[base + i1] = ui + vi;
            float dr = ur - vr, di = ui - vi;
            sre[base + i2] = dr * wr - di * wi;
            sim[base + i2] = dr * wi + di * wr;
        }
        __syncthreads();
    }

    // multiply by filter spectrum at bit-reversed position
    int pb = brev8(tid);
    for (int i = 0; i < 8; i++) {
        int k1 = (int)((rbase + i) & (N1 - 1));
        float2 g = G[(size_t)k1 * N2 + pb];
        float ar = sre[i * 256 + tid], ai = sim[i * 256 + tid];
        sre[i * 256 + tid] = ar * g.x - ai * g.y;
        sim[i * 256 + tid] = ar * g.y + ai * g.x;
    }
    __syncthreads();

    // inverse DIT: h = 1 .. 128, brev in -> natural out (+angle, unscaled)
    for (int s = 0; s < 8; s++) {
        int h = 1 << s;
        int base = rl * 256;
        for (int jj = 0; jj < 4; jj++) {
            int beta = jj * 32 + rr;
            int j  = beta & (h - 1);
            int i1 = ((beta >> s) << (s + 1)) | j;
            int i2 = i1 + h;
            float ang = PI_F * (float)j / (float)h;
            float wr = __cosf(ang), wi = __sinf(ang);
            float ur = sre[base + i1], ui = sim[base + i1];
            float vr = sre[base + i2], vi = sim[base + i2];
            float tr = vr * wr - vi * wi;
            float ti = vr * wi + vi * wr;
            sre[base + i1] = ur + tr; sim[base + i1] = ui + ti;
            sre[base + i2] = ur - tr; sim[base + i2] = ui - ti;
        }
        __syncthreads();
    }

    // conjugate big twiddle W_N^{-n2*k1} (inverse step-2), store
    for (int i = 0; i < 8; i++) {
        int k1 = (int)((rbase + i) & (N1 - 1));
        int n2 = tid;
        float ang = 2.f * PI_F * (float)(n2 * k1) / (float)N_FFT;
        float wr = __cosf(ang), wi = __sinf(ang);
        float ar = sre[i * 256 + tid], ai = sim[i * 256 + tid];
        gptr[i * 256 + tid] = make_float2(ar * wr - ai * wi, ar * wi + ai * wr);
    }
}

// ---------------------------------------------------------------------------
// Inverse column FFTs (length 512, stride 256), scale 1/N, emit first 65536
// samples: re -> out row 2b, im -> out row 2b+1.
// ---------------------------------------------------------------------------
__global__ __launch_bounds__(256) void inv_cols(
    const float2* __restrict__ src, float* __restrict__ out)
{
    const int tile = blockIdx.x;
    const int row  = blockIdx.y;
    const int tid  = threadIdx.x;
    __shared__ float sre[N1 * 16], sim[N1 * 16];
    const float2* srow = src + (size_t)row * N_FFT;
    const int n2base = tile * 16;

    for (int i = 0; i < 32; i++) {
        int idx = tid + i * 256;
        int k1 = idx >> 4;
        int cc = idx & 15;
        float2 v = srow[(size_t)k1 * N2 + n2base + cc];
        int p = brev9(k1);
        sre[p * 16 + cc] = v.x;
        sim[p * 16 + cc] = v.y;
    }
    __syncthreads();

    const int c = tid & 15;
    const int r = tid >> 4;
    for (int s = 0; s < 9; s++) {          // inverse DIT (+angle)
        int h = 1 << s;
        for (int jj = 0; jj < 16; jj++) {
            int beta = jj * 16 + r;
            int j  = beta & (h - 1);
            int i1 = ((beta >> s) << (s + 1)) | j;
            int i2 = i1 + h;
            float ang = PI_F * (float)j / (float)h;
            float wr = __cosf(ang), wi = __sinf(ang);
            float ur = sre[i1 * 16 + c], ui = sim[i1 * 16 + c];
            float vr = sre[i2 * 16 + c], vi = sim[i2 * 16 + c];
            float tr = vr * wr - vi * wi;
            float ti = vr * wi + vi * wr;
            sre[i1 * 16 + c] = ur + tr; sim[i1 * 16 + c] = ui + ti;
            sre[i2 * 16 + c] = ur - tr; sim[i2 * 16 + c] = ui - ti;
        }
        __syncthreads();
    }

    const float scale = 1.0f / (float)N_FFT;
    float* out0 = out + (size_t)(2 * row) * T_LEN;
    float* out1 = out + (size_t)(2 * row + 1) * T_LEN;
    for (int i = 0; i < 16; i++) {         // only n1 < 256 (n < 65536) kept
        int idx = tid + i * 256;
        int n1 = idx >> 4;
        int cc = idx & 15;
        int n = n1 * N2 + n2base + cc;
        out0[n] = sre[n1 * 16 + cc] * scale;
        out1[n] = sim[n1 * 16 + cc] * scale;
    }
}

extern "C" void kernel_launch(void* const* d_in, const int* in_sizes, int n_in,
                              void* d_out, int out_size, void* d_ws, size_t ws_size,
                              hipStream_t stream) {
    const float* x    = (const float*)d_in[0];   // (256, 65536) f32
    const float* filt = (const float*)d_in[1];   // (1, 65536) f32
    float* out = (float*)d_out;                  // (256, 65536) f32

    float2* bufA = (float2*)d_ws;                                   // 128 MB
    float2* G    = (float2*)((char*)d_ws + (size_t)CB * N_FFT * sizeof(float2)); // 1 MB

    // filter spectrum (same permuted transform as the data path)
    fwd_cols<<<dim3(16, 1), 256, 0, stream>>>(filt, nullptr, 0LL, G);
    fwd_rows_g<<<N1 / 8, 256, 0, stream>>>(G);

    // data forward columns (+twiddle)
    fwd_cols<<<dim3(16, CB), 256, 0, stream>>>(x, x + T_LEN, (long long)(2 * T_LEN), bufA);

    // fused: fwd rows -> xG -> inv rows -> conj twiddle
    mid_rows<<<(CB * N1) / 8, 256, 0, stream>>>(bufA, G);

    // inverse columns, scale, write output
    inv_cols<<<dim3(16, CB), 256, 0, stream>>>(bufA, out);
}

// Round 2
// 273.031 us; speedup vs baseline: 1.7244x; 1.7244x over previous
//
#include <hip/hip_runtime.h>

// Causal FIR conv via FFT (n_fft = 131072), four-step N = 512 x 256,
// transpose-free, batch-packed (2 real rows -> 1 complex row).
// v2: float2 LDS (b64), fused radix-4 double-stages, register octet stages,
// DIF forward (natural->brev relabeled at store) / DIT inverse.

#define N_FFT 131072
#define N1    512
#define N2    256
#define T_LEN 65536
#define CB    128
#define PI_F  3.14159265358979323846f
#define R2_F  0.70710678118654752f

__device__ inline int brev9(int x) { return (int)(__brev((unsigned)x) >> 23); }

__device__ inline float2 cadd(float2 a, float2 b){ return make_float2(a.x+b.x, a.y+b.y); }
__device__ inline float2 csub(float2 a, float2 b){ return make_float2(a.x-b.x, a.y-b.y); }
__device__ inline float2 cmul(float2 a, float2 b){ return make_float2(a.x*b.x-a.y*b.y, a.x*b.y+a.y*b.x); }
__device__ inline float2 expif(float a){ float s,c; __sincosf(a,&s,&c); return make_float2(c,s); }

// Fused DIF double stage (h then h/2), forward twiddles. quad (p0, p0+h/2, p0+h, p0+3h/2)
// w1 = W_{2h}^{j'}, w2 = w1^2
__device__ inline void dif4(float2&a0, float2&a1, float2&a2, float2&a3, float2 w1, float2 w2){
    float2 s02 = cadd(a0,a2), d02 = csub(a0,a2);
    float2 s13 = cadd(a1,a3), d13 = csub(a1,a3);
    float2 b2 = cmul(w1,d02);
    float2 t  = cmul(w1,d13);
    float2 b3 = make_float2(t.y, -t.x);          // -i*t
    a0 = cadd(s02,s13);
    a1 = cmul(w2, csub(s02,s13));
    a2 = cadd(b2,b3);
    a3 = cmul(w2, csub(b2,b3));
}

// Fused DIT double stage (h then 2h), INVERSE twiddles. quad (p0, p0+h, p0+2h, p0+3h)
// w1 = conj(W_{2h}^j) = w2^2, w2 = conj(W_{4h}^j)
__device__ inline void dit4i(float2&a0, float2&a1, float2&a2, float2&a3, float2 w1, float2 w2){
    float2 t1 = cmul(w1,a1), t3 = cmul(w1,a3);
    float2 u0 = cadd(a0,t1), u1 = csub(a0,t1);
    float2 u2 = cadd(a2,t3), u3 = csub(a2,t3);
    float2 s2 = cmul(w2,u2), s3 = cmul(w2,u3);
    a0 = cadd(u0,s2); a2 = csub(u0,s2);
    a1 = make_float2(u1.x - s3.y, u1.y + s3.x);  // u1 + i*s3
    a3 = make_float2(u1.x + s3.y, u1.y - s3.x);  // u1 - i*s3
}

// ---------------------------------------------------------------------------
// Forward column FFT (512-pt, DIF) over n1, 16 columns/block, + big twiddle,
// store at natural k1 = brev9(p). Upper half (n1>=256) implicit zero.
// ---------------------------------------------------------------------------
__global__ __launch_bounds__(256) void fwd_cols(
    const float* __restrict__ re_base, const float* __restrict__ im_base,
    long long row_stride, float2* __restrict__ dst)
{
    __shared__ float2 s[N1 * 16];                 // 64 KB, bank = 2c always
    const int tile = blockIdx.x, row = blockIdx.y, tid = threadIdx.x;
    const int n2base = tile * 16;
    const float* rp = re_base + (long long)row * row_stride;
    const float* ip = im_base ? (im_base + (long long)row * row_stride) : nullptr;

    // coop load n1 in [0,256): pack (row0, row1) as (re, im); float2 global reads
    {
        const int cp = tid & 7, n1g = tid >> 3;
#pragma unroll
        for (int i = 0; i < 8; i++) {
            int n1 = n1g + 32 * i;
            int g  = n1 * N2 + n2base + 2 * cp;
            float2 a = *(const float2*)(rp + g);
            float2 b = ip ? *(const float2*)(ip + g) : make_float2(0.f, 0.f);
            s[n1 * 16 + 2 * cp]     = make_float2(a.x, b.x);
            s[n1 * 16 + 2 * cp + 1] = make_float2(a.y, b.y);
        }
    }
    __syncthreads();

    const int c = tid & 15, r = tid >> 4;

    // fused (256,128): p2,p3 inputs are zero (padding) -> read 2, write 4
#pragma unroll
    for (int qq = 0; qq < 8; qq++) {
        int j = r + 16 * qq;                      // 0..127
        float2 w1 = expif((float)j * (-PI_F / 256.f));
        float2 w2 = cmul(w1, w1);
        float2 a0 = s[j * 16 + c], a1 = s[(j + 128) * 16 + c];
        float2 b2 = cmul(w1, a0);
        float2 t  = cmul(w1, a1);
        float2 b3 = make_float2(t.y, -t.x);
        s[j * 16 + c]         = cadd(a0, a1);
        s[(j + 128) * 16 + c] = cmul(w2, csub(a0, a1));
        s[(j + 256) * 16 + c] = cadd(b2, b3);
        s[(j + 384) * 16 + c] = cmul(w2, csub(b2, b3));
    }
    __syncthreads();

    // fused (64,32)
#pragma unroll
    for (int qq = 0; qq < 8; qq++) {
        int q = r + 16 * qq, j = q & 31, g = q >> 5;
        int p0 = g * 128 + j;
        float2 w1 = expif((float)j * (-PI_F / 64.f));
        float2 w2 = cmul(w1, w1);
        float2 a0 = s[p0*16+c], a1 = s[(p0+32)*16+c], a2 = s[(p0+64)*16+c], a3 = s[(p0+96)*16+c];
        dif4(a0, a1, a2, a3, w1, w2);
        s[p0*16+c] = a0; s[(p0+32)*16+c] = a1; s[(p0+64)*16+c] = a2; s[(p0+96)*16+c] = a3;
    }
    __syncthreads();

    // fused (16,8)
#pragma unroll
    for (int qq = 0; qq < 8; qq++) {
        int q = r + 16 * qq, j = q & 7, g = q >> 3;
        int p0 = g * 32 + j;
        float2 w1 = expif((float)j * (-PI_F / 16.f));
        float2 w2 = cmul(w1, w1);
        float2 a0 = s[p0*16+c], a1 = s[(p0+8)*16+c], a2 = s[(p0+16)*16+c], a3 = s[(p0+24)*16+c];
        dif4(a0, a1, a2, a3, w1, w2);
        s[p0*16+c] = a0; s[(p0+8)*16+c] = a1; s[(p0+16)*16+c] = a2; s[(p0+24)*16+c] = a3;
    }
    __syncthreads();

    // register octets: fused (4,2) + h=1, then big twiddle + store (k1 = brev9(p))
    float2* drow = dst + (size_t)row * N_FFT;
    const int n2 = n2base + c;
    const float2 w1c = make_float2(R2_F, -R2_F);  // W_8^1
    const float2 w2c = make_float2(0.f, -1.f);    // W_4^1
    const float2 one = make_float2(1.f, 0.f);
#pragma unroll
    for (int o = 0; o < 4; o++) {
        int base = 8 * (r + 16 * o);
        float2 v[8];
#pragma unroll
        for (int m = 0; m < 8; m++) v[m] = s[(base + m) * 16 + c];
        dif4(v[0], v[2], v[4], v[6], one, one);
        dif4(v[1], v[3], v[5], v[7], w1c, w2c);
#pragma unroll
        for (int m = 0; m < 8; m += 2) {
            float2 a = v[m], b = v[m + 1];
            v[m] = cadd(a, b); v[m + 1] = csub(a, b);
        }
#pragma unroll
        for (int m = 0; m < 8; m++) {
            int p  = base + m;
            int k1 = brev9(p);
            float2 w = expif((float)(n2 * k1) * (-2.f * PI_F / (float)N_FFT));
            drow[(size_t)k1 * N2 + n2] = cmul(v[m], w);
        }
    }
}

// ---------------------------------------------------------------------------
// Filter row FFTs: 256-pt forward DIF per k1-row, leave in brev order.
// ---------------------------------------------------------------------------
#define MROW 292
#define MIDX(rw, p) ((rw) * MROW + (p) + ((p) >> 3))

__global__ __launch_bounds__(256) void fwd_rows_g(float2* __restrict__ G)
{
    __shared__ float2 s[8 * MROW];
    const int tid = threadIdx.x;
    const long long rbase = (long long)blockIdx.x * 8;
#pragma unroll
    for (int i = 0; i < 8; i++) {
        int e = tid + 256 * i, rw = e >> 8, p = e & 255;
        s[MIDX(rw, p)] = G[(rbase + rw) * N2 + p];
    }
    __syncthreads();
    const int rl = tid >> 5, rr = tid & 31;
    // fused (128,64)
#pragma unroll
    for (int qq = 0; qq < 2; qq++) {
        int j = rr + 32 * qq;
        float2 w1 = expif((float)j * (-PI_F / 128.f)), w2 = cmul(w1, w1);
        float2 a0=s[MIDX(rl,j)], a1=s[MIDX(rl,j+64)], a2=s[MIDX(rl,j+128)], a3=s[MIDX(rl,j+192)];
        dif4(a0,a1,a2,a3,w1,w2);
        s[MIDX(rl,j)]=a0; s[MIDX(rl,j+64)]=a1; s[MIDX(rl,j+128)]=a2; s[MIDX(rl,j+192)]=a3;
    }
    __syncthreads();
    // fused (32,16)
#pragma unroll
    for (int qq = 0; qq < 2; qq++) {
        int q = rr + 32 * qq, j = q & 15, g = q >> 4, p0 = g * 64 + j;
        float2 w1 = expif((float)j * (-PI_F / 32.f)), w2 = cmul(w1, w1);
        float2 a0=s[MIDX(rl,p0)], a1=s[MIDX(rl,p0+16)], a2=s[MIDX(rl,p0+32)], a3=s[MIDX(rl,p0+48)];
        dif4(a0,a1,a2,a3,w1,w2);
        s[MIDX(rl,p0)]=a0; s[MIDX(rl,p0+16)]=a1; s[MIDX(rl,p0+32)]=a2; s[MIDX(rl,p0+48)]=a3;
    }
    __syncthreads();
    // fused (8,4)
#pragma unroll
    for (int qq = 0; qq < 2; qq++) {
        int q = rr + 32 * qq, j = q & 3, g = q >> 2, p0 = g * 16 + j;
        float2 w1 = expif((float)j * (-PI_F / 8.f)), w2 = cmul(w1, w1);
        float2 a0=s[MIDX(rl,p0)], a1=s[MIDX(rl,p0+4)], a2=s[MIDX(rl,p0+8)], a3=s[MIDX(rl,p0+12)];
        dif4(a0,a1,a2,a3,w1,w2);
        s[MIDX(rl,p0)]=a0; s[MIDX(rl,p0+4)]=a1; s[MIDX(rl,p0+8)]=a2; s[MIDX(rl,p0+12)]=a3;
    }
    __syncthreads();
    // register fused (2,1): twiddle-free
#pragma unroll
    for (int qq = 0; qq < 2; qq++) {
        int base = 4 * (rr + 32 * qq);
        float2 a0=s[MIDX(rl,base)], a1=s[MIDX(rl,base+1)], a2=s[MIDX(rl,base+2)], a3=s[MIDX(rl,base+3)];
        float2 s02 = cadd(a0,a2), d02 = csub(a0,a2);
        float2 s13 = cadd(a1,a3), d13 = csub(a1,a3);
        float2 b3 = make_float2(d13.y, -d13.x);
        s[MIDX(rl,base)]   = cadd(s02,s13);
        s[MIDX(rl,base+1)] = csub(s02,s13);
        s[MIDX(rl,base+2)] = cadd(d02,b3);
        s[MIDX(rl,base+3)] = csub(d02,b3);
    }
    __syncthreads();
#pragma unroll
    for (int i = 0; i < 8; i++) {
        int e = tid + 256 * i, rw = e >> 8, p = e & 255;
        G[(rbase + rw) * N2 + p] = s[MIDX(rw, p)];
    }
}

// ---------------------------------------------------------------------------
// Fused mid: fwd row DIF -> x G(brev order) -> inv row DIT -> conj big twiddle
// ---------------------------------------------------------------------------
__global__ __launch_bounds__(256) void mid_rows(
    float2* __restrict__ buf, const float2* __restrict__ Gb)
{
    __shared__ float2 s[8 * MROW];
    const int tid = threadIdx.x;
    const long long rbase = (long long)blockIdx.x * 8;
#pragma unroll
    for (int i = 0; i < 8; i++) {
        int e = tid + 256 * i, rw = e >> 8, p = e & 255;
        s[MIDX(rw, p)] = buf[(rbase + rw) * N2 + p];
    }
    __syncthreads();
    const int rl = tid >> 5, rr = tid & 31;
    const int k1 = (int)((rbase + rl) & (N1 - 1));

    // ---- forward DIF ----
#pragma unroll
    for (int qq = 0; qq < 2; qq++) {
        int j = rr + 32 * qq;
        float2 w1 = expif((float)j * (-PI_F / 128.f)), w2 = cmul(w1, w1);
        float2 a0=s[MIDX(rl,j)], a1=s[MIDX(rl,j+64)], a2=s[MIDX(rl,j+128)], a3=s[MIDX(rl,j+192)];
        dif4(a0,a1,a2,a3,w1,w2);
        s[MIDX(rl,j)]=a0; s[MIDX(rl,j+64)]=a1; s[MIDX(rl,j+128)]=a2; s[MIDX(rl,j+192)]=a3;
    }
    __syncthreads();
#pragma unroll
    for (int qq = 0; qq < 2; qq++) {
        int q = rr + 32 * qq, j = q & 15, g = q >> 4, p0 = g * 64 + j;
        float2 w1 = expif((float)j * (-PI_F / 32.f)), w2 = cmul(w1, w1);
        float2 a0=s[MIDX(rl,p0)], a1=s[MIDX(rl,p0+16)], a2=s[MIDX(rl,p0+32)], a3=s[MIDX(rl,p0+48)];
        dif4(a0,a1,a2,a3,w1,w2);
        s[MIDX(rl,p0)]=a0; s[MIDX(rl,p0+16)]=a1; s[MIDX(rl,p0+32)]=a2; s[MIDX(rl,p0+48)]=a3;
    }
    __syncthreads();
#pragma unroll
    for (int qq = 0; qq < 2; qq++) {
        int q = rr + 32 * qq, j = q & 3, g = q >> 2, p0 = g * 16 + j;
        float2 w1 = expif((float)j * (-PI_F / 8.f)), w2 = cmul(w1, w1);
        float2 a0=s[MIDX(rl,p0)], a1=s[MIDX(rl,p0+4)], a2=s[MIDX(rl,p0+8)], a3=s[MIDX(rl,p0+12)];
        dif4(a0,a1,a2,a3,w1,w2);
        s[MIDX(rl,p0)]=a0; s[MIDX(rl,p0+4)]=a1; s[MIDX(rl,p0+8)]=a2; s[MIDX(rl,p0+12)]=a3;
    }
    __syncthreads();

    // ---- register: fused(2,1) -> xG -> inverse fused(1,2) ----
    const float2* grow = Gb + (size_t)k1 * N2;
#pragma unroll
    for (int qq = 0; qq < 2; qq++) {
        int base = 4 * (rr + 32 * qq);
        float2 a0=s[MIDX(rl,base)], a1=s[MIDX(rl,base+1)], a2=s[MIDX(rl,base+2)], a3=s[MIDX(rl,base+3)];
        // fwd fused(2,1), twiddle-free
        float2 s02 = cadd(a0,a2), d02 = csub(a0,a2);
        float2 s13 = cadd(a1,a3), d13 = csub(a1,a3);
        float2 b3 = make_float2(d13.y, -d13.x);
        float2 v0 = cadd(s02,s13), v1 = csub(s02,s13), v2 = cadd(d02,b3), v3 = csub(d02,b3);
        // pointwise x Ghat (both brev-ordered)
        v0 = cmul(v0, grow[base]);   v1 = cmul(v1, grow[base+1]);
        v2 = cmul(v2, grow[base+2]); v3 = cmul(v3, grow[base+3]);
        // inverse fused(1,2), twiddle-free
        float2 u0 = cadd(v0,v1), u1 = csub(v0,v1);
        float2 u2 = cadd(v2,v3), u3 = csub(v2,v3);
        s[MIDX(rl,base)]   = cadd(u0,u2);
        s[MIDX(rl,base+2)] = csub(u0,u2);
        s[MIDX(rl,base+1)] = make_float2(u1.x - u3.y, u1.y + u3.x);
        s[MIDX(rl,base+3)] = make_float2(u1.x + u3.y, u1.y - u3.x);
    }
    __syncthreads();

    // ---- inverse DIT ----
#pragma unroll
    for (int qq = 0; qq < 2; qq++) {
        int q = rr + 32 * qq, j = q & 3, g = q >> 2, p0 = g * 16 + j;
        float2 w2 = expif((float)j * (PI_F / 8.f)), w1 = cmul(w2, w2);
        float2 a0=s[MIDX(rl,p0)], a1=s[MIDX(rl,p0+4)], a2=s[MIDX(rl,p0+8)], a3=s[MIDX(rl,p0+12)];
        dit4i(a0,a1,a2,a3,w1,w2);
        s[MIDX(rl,p0)]=a0; s[MIDX(rl,p0+4)]=a1; s[MIDX(rl,p0+8)]=a2; s[MIDX(rl,p0+12)]=a3;
    }
    __syncthreads();
#pragma unroll
    for (int qq = 0; qq < 2; qq++) {
        int q = rr + 32 * qq, j = q & 15, g = q >> 4, p0 = g * 64 + j;
        float2 w2 = expif((float)j * (PI_F / 32.f)), w1 = cmul(w2, w2);
        float2 a0=s[MIDX(rl,p0)], a1=s[MIDX(rl,p0+16)], a2=s[MIDX(rl,p0+32)], a3=s[MIDX(rl,p0+48)];
        dit4i(a0,a1,a2,a3,w1,w2);
        s[MIDX(rl,p0)]=a0; s[MIDX(rl,p0+16)]=a1; s[MIDX(rl,p0+32)]=a2; s[MIDX(rl,p0+48)]=a3;
    }
    __syncthreads();
#pragma unroll
    for (int qq = 0; qq < 2; qq++) {
        int j = rr + 32 * qq;
        float2 w2 = expif((float)j * (PI_F / 128.f)), w1 = cmul(w2, w2);
        float2 a0=s[MIDX(rl,j)], a1=s[MIDX(rl,j+64)], a2=s[MIDX(rl,j+128)], a3=s[MIDX(rl,j+192)];
        dit4i(a0,a1,a2,a3,w1,w2);
        s[MIDX(rl,j)]=a0; s[MIDX(rl,j+64)]=a1; s[MIDX(rl,j+128)]=a2; s[MIDX(rl,j+192)]=a3;
    }
    __syncthreads();

    // conj big twiddle + store
#pragma unroll
    for (int i = 0; i < 8; i++) {
        int e = tid + 256 * i, rw = e >> 8, p = e & 255;
        int kk = (int)((rbase + rw) & (N1 - 1));
        float2 w = expif((float)(p * kk) * (2.f * PI_F / (float)N_FFT));
        buf[(rbase + rw) * N2 + p] = cmul(s[MIDX(rw, p)], w);
    }
}

// ---------------------------------------------------------------------------
// Inverse column FFT (512-pt DIT, brev load) over k1, scale, keep n1<256.
// ---------------------------------------------------------------------------
__global__ __launch_bounds__(256) void inv_cols(
    const float2* __restrict__ src, float* __restrict__ out)
{
    __shared__ float2 s[N1 * 16];
    const int tile = blockIdx.x, row = blockIdx.y, tid = threadIdx.x;
    const int n2base = tile * 16;
    const int c = tid & 15, r = tid >> 4;
    const float2* srow = src + (size_t)row * N_FFT;

#pragma unroll
    for (int i = 0; i < 32; i++) {
        int k1 = r + 16 * i;
        s[brev9(k1) * 16 + c] = srow[(size_t)k1 * N2 + n2base + c];
    }
    __syncthreads();

    // register octets: h=1 then fused (2,4), inverse constants
    const float2 w1c = make_float2(0.f, 1.f);     // conj(W_4^1) = i
    const float2 w2c = make_float2(R2_F, R2_F);   // conj(W_8^1)
    const float2 one = make_float2(1.f, 0.f);
#pragma unroll
    for (int o = 0; o < 4; o++) {
        int base = 8 * (r + 16 * o);
        float2 v[8];
#pragma unroll
        for (int m = 0; m < 8; m++) v[m] = s[(base + m) * 16 + c];
#pragma unroll
        for (int m = 0; m < 8; m += 2) {
            float2 a = v[m], b = v[m + 1];
            v[m] = cadd(a, b); v[m + 1] = csub(a, b);
        }
        dit4i(v[0], v[2], v[4], v[6], one, one);
        dit4i(v[1], v[3], v[5], v[7], w1c, w2c);
#pragma unroll
        for (int m = 0; m < 8; m++) s[(base + m) * 16 + c] = v[m];
    }
    __syncthreads();

    // fused (8,16)
#pragma unroll
    for (int qq = 0; qq < 8; qq++) {
        int q = r + 16 * qq, j = q & 7, g = q >> 3, p0 = g * 32 + j;
        float2 w2 = expif((float)j * (PI_F / 16.f)), w1 = cmul(w2, w2);
        float2 a0 = s[p0*16+c], a1 = s[(p0+8)*16+c], a2 = s[(p0+16)*16+c], a3 = s[(p0+24)*16+c];
        dit4i(a0, a1, a2, a3, w1, w2);
        s[p0*16+c] = a0; s[(p0+8)*16+c] = a1; s[(p0+16)*16+c] = a2; s[(p0+24)*16+c] = a3;
    }
    __syncthreads();
    // fused (32,64)
#pragma unroll
    for (int qq = 0; qq < 8; qq++) {
        int q = r + 16 * qq, j = q & 31, g = q >> 5, p0 = g * 128 + j;
        float2 w2 = expif((float)j * (PI_F / 64.f)), w1 = cmul(w2, w2);
        float2 a0 = s[p0*16+c], a1 = s[(p0+32)*16+c], a2 = s[(p0+64)*16+c], a3 = s[(p0+96)*16+c];
        dit4i(a0, a1, a2, a3, w1, w2);
        s[p0*16+c] = a0; s[(p0+32)*16+c] = a1; s[(p0+64)*16+c] = a2; s[(p0+96)*16+c] = a3;
    }
    __syncthreads();
    // fused (128,256)
#pragma unroll
    for (int qq = 0; qq < 8; qq++) {
        int j = r + 16 * qq;
        float2 w2 = expif((float)j * (PI_F / 256.f)), w1 = cmul(w2, w2);
        float2 a0 = s[j*16+c], a1 = s[(j+128)*16+c], a2 = s[(j+256)*16+c], a3 = s[(j+384)*16+c];
        dit4i(a0, a1, a2, a3, w1, w2);
        s[j*16+c] = a0; s[(j+128)*16+c] = a1; s[(j+256)*16+c] = a2; s[(j+384)*16+c] = a3;
    }
    __syncthreads();

    const float scale = 1.0f / (float)N_FFT;
    float* out0 = out + (size_t)(2 * row) * T_LEN;
    float* out1 = out + (size_t)(2 * row + 1) * T_LEN;
#pragma unroll
    for (int i = 0; i < 16; i++) {
        int p = r + 16 * i;                        // p < 256 only
        int n = p * N2 + n2base + c;
        float2 v = s[p * 16 + c];
        out0[n] = v.x * scale;
        out1[n] = v.y * scale;
    }
}

extern "C" void kernel_launch(void* const* d_in, const int* in_sizes, int n_in,
                              void* d_out, int out_size, void* d_ws, size_t ws_size,
                              hipStream_t stream) {
    const float* x    = (const float*)d_in[0];
    const float* filt = (const float*)d_in[1];
    float* out = (float*)d_out;

    float2* buf = (float2*)d_ws;                                               // 128 MB
    float2* G   = (float2*)((char*)d_ws + (size_t)CB * N_FFT * sizeof(float2)); // 1 MB

    fwd_cols<<<dim3(16, 1), 256, 0, stream>>>(filt, nullptr, 0LL, G);
    fwd_rows_g<<<N1 / 8, 256, 0, stream>>>(G);
    fwd_cols<<<dim3(16, CB), 256, 0, stream>>>(x, x + T_LEN, (long long)(2 * T_LEN), buf);
    mid_rows<<<(CB * N1) / 8, 256, 0, stream>>>(buf, G);
    inv_cols<<<dim3(16, CB), 256, 0, stream>>>(buf, out);
}

// Round 3
// 254.322 us; speedup vs baseline: 1.8513x; 1.0736x over previous
//
#include <hip/hip_runtime.h>

// Causal FIR conv via FFT (n_fft = 131072), four-step N = 512 x 256,
// transpose-free, batch-packed (2 real rows -> 1 complex row).
// v3: column kernels at 512 threads/block (16 waves/CU resident vs 8) —
// same 64 KB LDS tile, half the per-thread work, double the latency hiding.

#define N_FFT 131072
#define N1    512
#define N2    256
#define T_LEN 65536
#define CB    128
#define PI_F  3.14159265358979323846f
#define R2_F  0.70710678118654752f

__device__ inline int brev9(int x) { return (int)(__brev((unsigned)x) >> 23); }

__device__ inline float2 cadd(float2 a, float2 b){ return make_float2(a.x+b.x, a.y+b.y); }
__device__ inline float2 csub(float2 a, float2 b){ return make_float2(a.x-b.x, a.y-b.y); }
__device__ inline float2 cmul(float2 a, float2 b){ return make_float2(a.x*b.x-a.y*b.y, a.x*b.y+a.y*b.x); }
__device__ inline float2 expif(float a){ float s,c; __sincosf(a,&s,&c); return make_float2(c,s); }

// Fused DIF double stage (h then h/2). quad (p0, p0+h/2, p0+h, p0+3h/2)
__device__ inline void dif4(float2&a0, float2&a1, float2&a2, float2&a3, float2 w1, float2 w2){
    float2 s02 = cadd(a0,a2), d02 = csub(a0,a2);
    float2 s13 = cadd(a1,a3), d13 = csub(a1,a3);
    float2 b2 = cmul(w1,d02);
    float2 t  = cmul(w1,d13);
    float2 b3 = make_float2(t.y, -t.x);          // -i*t
    a0 = cadd(s02,s13);
    a1 = cmul(w2, csub(s02,s13));
    a2 = cadd(b2,b3);
    a3 = cmul(w2, csub(b2,b3));
}

// Fused DIT double stage (h then 2h), inverse twiddles. quad (p0, p0+h, p0+2h, p0+3h)
__device__ inline void dit4i(float2&a0, float2&a1, float2&a2, float2&a3, float2 w1, float2 w2){
    float2 t1 = cmul(w1,a1), t3 = cmul(w1,a3);
    float2 u0 = cadd(a0,t1), u1 = csub(a0,t1);
    float2 u2 = cadd(a2,t3), u3 = csub(a2,t3);
    float2 s2 = cmul(w2,u2), s3 = cmul(w2,u3);
    a0 = cadd(u0,s2); a2 = csub(u0,s2);
    a1 = make_float2(u1.x - s3.y, u1.y + s3.x);  // u1 + i*s3
    a3 = make_float2(u1.x + s3.y, u1.y - s3.x);  // u1 - i*s3
}

// ---------------------------------------------------------------------------
// Forward column FFT (512-pt DIF) over n1, 16 columns/block, + big twiddle,
// store at natural k1 = brev9(p). Upper half (n1>=256) implicit zero.
// 512 threads: r = tid>>4 in [0,32), c = tid&15.
// ---------------------------------------------------------------------------
__global__ __launch_bounds__(512, 4) void fwd_cols(
    const float* __restrict__ re_base, const float* __restrict__ im_base,
    long long row_stride, float2* __restrict__ dst)
{
    __shared__ float2 s[N1 * 16];                 // 64 KB, bank = 2c always
    const int tile = blockIdx.x, row = blockIdx.y, tid = threadIdx.x;
    const int n2base = tile * 16;
    const float* rp = re_base + (long long)row * row_stride;
    const float* ip = im_base ? (im_base + (long long)row * row_stride) : nullptr;

    // coop load n1 in [0,256): pack (row0, row1) as (re, im)
    {
        const int cp = tid & 7, n1g = tid >> 3;   // n1g in [0,64)
#pragma unroll
        for (int i = 0; i < 4; i++) {
            int n1 = n1g + 64 * i;
            int g  = n1 * N2 + n2base + 2 * cp;
            float2 a = *(const float2*)(rp + g);
            float2 b = ip ? *(const float2*)(ip + g) : make_float2(0.f, 0.f);
            s[n1 * 16 + 2 * cp]     = make_float2(a.x, b.x);
            s[n1 * 16 + 2 * cp + 1] = make_float2(a.y, b.y);
        }
    }
    __syncthreads();

    const int c = tid & 15, r = tid >> 4;         // r in [0,32)

    // fused (256,128): p2,p3 inputs are zero (padding) -> read 2, write 4
#pragma unroll
    for (int qq = 0; qq < 4; qq++) {
        int j = r + 32 * qq;                      // 0..127
        float2 w1 = expif((float)j * (-PI_F / 256.f));
        float2 w2 = cmul(w1, w1);
        float2 a0 = s[j * 16 + c], a1 = s[(j + 128) * 16 + c];
        float2 b2 = cmul(w1, a0);
        float2 t  = cmul(w1, a1);
        float2 b3 = make_float2(t.y, -t.x);
        s[j * 16 + c]         = cadd(a0, a1);
        s[(j + 128) * 16 + c] = cmul(w2, csub(a0, a1));
        s[(j + 256) * 16 + c] = cadd(b2, b3);
        s[(j + 384) * 16 + c] = cmul(w2, csub(b2, b3));
    }
    __syncthreads();

    // fused (64,32)
#pragma unroll
    for (int qq = 0; qq < 4; qq++) {
        int q = r + 32 * qq, j = q & 31, g = q >> 5;
        int p0 = g * 128 + j;
        float2 w1 = expif((float)j * (-PI_F / 64.f));
        float2 w2 = cmul(w1, w1);
        float2 a0 = s[p0*16+c], a1 = s[(p0+32)*16+c], a2 = s[(p0+64)*16+c], a3 = s[(p0+96)*16+c];
        dif4(a0, a1, a2, a3, w1, w2);
        s[p0*16+c] = a0; s[(p0+32)*16+c] = a1; s[(p0+64)*16+c] = a2; s[(p0+96)*16+c] = a3;
    }
    __syncthreads();

    // fused (16,8)
#pragma unroll
    for (int qq = 0; qq < 4; qq++) {
        int q = r + 32 * qq, j = q & 7, g = q >> 3;
        int p0 = g * 32 + j;
        float2 w1 = expif((float)j * (-PI_F / 16.f));
        float2 w2 = cmul(w1, w1);
        float2 a0 = s[p0*16+c], a1 = s[(p0+8)*16+c], a2 = s[(p0+16)*16+c], a3 = s[(p0+24)*16+c];
        dif4(a0, a1, a2, a3, w1, w2);
        s[p0*16+c] = a0; s[(p0+8)*16+c] = a1; s[(p0+16)*16+c] = a2; s[(p0+24)*16+c] = a3;
    }
    __syncthreads();

    // register octets: fused (4,2) + h=1, then big twiddle + store (k1 = brev9(p))
    float2* drow = dst + (size_t)row * N_FFT;
    const int n2 = n2base + c;
    const float2 w1c = make_float2(R2_F, -R2_F);  // W_8^1
    const float2 w2c = make_float2(0.f, -1.f);    // W_4^1
    const float2 one = make_float2(1.f, 0.f);
#pragma unroll
    for (int o = 0; o < 2; o++) {
        int base = 8 * (r + 32 * o);
        float2 v[8];
#pragma unroll
        for (int m = 0; m < 8; m++) v[m] = s[(base + m) * 16 + c];
        dif4(v[0], v[2], v[4], v[6], one, one);
        dif4(v[1], v[3], v[5], v[7], w1c, w2c);
#pragma unroll
        for (int m = 0; m < 8; m += 2) {
            float2 a = v[m], b = v[m + 1];
            v[m] = cadd(a, b); v[m + 1] = csub(a, b);
        }
#pragma unroll
        for (int m = 0; m < 8; m++) {
            int p  = base + m;
            int k1 = brev9(p);
            float2 w = expif((float)(n2 * k1) * (-2.f * PI_F / (float)N_FFT));
            drow[(size_t)k1 * N2 + n2] = cmul(v[m], w);
        }
    }
}

// ---------------------------------------------------------------------------
// Filter row FFTs: 256-pt forward DIF per k1-row, leave in brev order.
// ---------------------------------------------------------------------------
#define MROW 292
#define MIDX(rw, p) ((rw) * MROW + (p) + ((p) >> 3))

__global__ __launch_bounds__(256) void fwd_rows_g(float2* __restrict__ G)
{
    __shared__ float2 s[8 * MROW];
    const int tid = threadIdx.x;
    const long long rbase = (long long)blockIdx.x * 8;
#pragma unroll
    for (int i = 0; i < 8; i++) {
        int e = tid + 256 * i, rw = e >> 8, p = e & 255;
        s[MIDX(rw, p)] = G[(rbase + rw) * N2 + p];
    }
    __syncthreads();
    const int rl = tid >> 5, rr = tid & 31;
#pragma unroll
    for (int qq = 0; qq < 2; qq++) {
        int j = rr + 32 * qq;
        float2 w1 = expif((float)j * (-PI_F / 128.f)), w2 = cmul(w1, w1);
        float2 a0=s[MIDX(rl,j)], a1=s[MIDX(rl,j+64)], a2=s[MIDX(rl,j+128)], a3=s[MIDX(rl,j+192)];
        dif4(a0,a1,a2,a3,w1,w2);
        s[MIDX(rl,j)]=a0; s[MIDX(rl,j+64)]=a1; s[MIDX(rl,j+128)]=a2; s[MIDX(rl,j+192)]=a3;
    }
    __syncthreads();
#pragma unroll
    for (int qq = 0; qq < 2; qq++) {
        int q = rr + 32 * qq, j = q & 15, g = q >> 4, p0 = g * 64 + j;
        float2 w1 = expif((float)j * (-PI_F / 32.f)), w2 = cmul(w1, w1);
        float2 a0=s[MIDX(rl,p0)], a1=s[MIDX(rl,p0+16)], a2=s[MIDX(rl,p0+32)], a3=s[MIDX(rl,p0+48)];
        dif4(a0,a1,a2,a3,w1,w2);
        s[MIDX(rl,p0)]=a0; s[MIDX(rl,p0+16)]=a1; s[MIDX(rl,p0+32)]=a2; s[MIDX(rl,p0+48)]=a3;
    }
    __syncthreads();
#pragma unroll
    for (int qq = 0; qq < 2; qq++) {
        int q = rr + 32 * qq, j = q & 3, g = q >> 2, p0 = g * 16 + j;
        float2 w1 = expif((float)j * (-PI_F / 8.f)), w2 = cmul(w1, w1);
        float2 a0=s[MIDX(rl,p0)], a1=s[MIDX(rl,p0+4)], a2=s[MIDX(rl,p0+8)], a3=s[MIDX(rl,p0+12)];
        dif4(a0,a1,a2,a3,w1,w2);
        s[MIDX(rl,p0)]=a0; s[MIDX(rl,p0+4)]=a1; s[MIDX(rl,p0+8)]=a2; s[MIDX(rl,p0+12)]=a3;
    }
    __syncthreads();
#pragma unroll
    for (int qq = 0; qq < 2; qq++) {
        int base = 4 * (rr + 32 * qq);
        float2 a0=s[MIDX(rl,base)], a1=s[MIDX(rl,base+1)], a2=s[MIDX(rl,base+2)], a3=s[MIDX(rl,base+3)];
        float2 s02 = cadd(a0,a2), d02 = csub(a0,a2);
        float2 s13 = cadd(a1,a3), d13 = csub(a1,a3);
        float2 b3 = make_float2(d13.y, -d13.x);
        s[MIDX(rl,base)]   = cadd(s02,s13);
        s[MIDX(rl,base+1)] = csub(s02,s13);
        s[MIDX(rl,base+2)] = cadd(d02,b3);
        s[MIDX(rl,base+3)] = csub(d02,b3);
    }
    __syncthreads();
#pragma unroll
    for (int i = 0; i < 8; i++) {
        int e = tid + 256 * i, rw = e >> 8, p = e & 255;
        G[(rbase + rw) * N2 + p] = s[MIDX(rw, p)];
    }
}

// ---------------------------------------------------------------------------
// Fused mid: fwd row DIF -> x G(brev order) -> inv row DIT -> conj big twiddle
// ---------------------------------------------------------------------------
__global__ __launch_bounds__(256) void mid_rows(
    float2* __restrict__ buf, const float2* __restrict__ Gb)
{
    __shared__ float2 s[8 * MROW];
    const int tid = threadIdx.x;
    const long long rbase = (long long)blockIdx.x * 8;
#pragma unroll
    for (int i = 0; i < 8; i++) {
        int e = tid + 256 * i, rw = e >> 8, p = e & 255;
        s[MIDX(rw, p)] = buf[(rbase + rw) * N2 + p];
    }
    __syncthreads();
    const int rl = tid >> 5, rr = tid & 31;
    const int k1 = (int)((rbase + rl) & (N1 - 1));

    // ---- forward DIF ----
#pragma unroll
    for (int qq = 0; qq < 2; qq++) {
        int j = rr + 32 * qq;
        float2 w1 = expif((float)j * (-PI_F / 128.f)), w2 = cmul(w1, w1);
        float2 a0=s[MIDX(rl,j)], a1=s[MIDX(rl,j+64)], a2=s[MIDX(rl,j+128)], a3=s[MIDX(rl,j+192)];
        dif4(a0,a1,a2,a3,w1,w2);
        s[MIDX(rl,j)]=a0; s[MIDX(rl,j+64)]=a1; s[MIDX(rl,j+128)]=a2; s[MIDX(rl,j+192)]=a3;
    }
    __syncthreads();
#pragma unroll
    for (int qq = 0; qq < 2; qq++) {
        int q = rr + 32 * qq, j = q & 15, g = q >> 4, p0 = g * 64 + j;
        float2 w1 = expif((float)j * (-PI_F / 32.f)), w2 = cmul(w1, w1);
        float2 a0=s[MIDX(rl,p0)], a1=s[MIDX(rl,p0+16)], a2=s[MIDX(rl,p0+32)], a3=s[MIDX(rl,p0+48)];
        dif4(a0,a1,a2,a3,w1,w2);
        s[MIDX(rl,p0)]=a0; s[MIDX(rl,p0+16)]=a1; s[MIDX(rl,p0+32)]=a2; s[MIDX(rl,p0+48)]=a3;
    }
    __syncthreads();
#pragma unroll
    for (int qq = 0; qq < 2; qq++) {
        int q = rr + 32 * qq, j = q & 3, g = q >> 2, p0 = g * 16 + j;
        float2 w1 = expif((float)j * (-PI_F / 8.f)), w2 = cmul(w1, w1);
        float2 a0=s[MIDX(rl,p0)], a1=s[MIDX(rl,p0+4)], a2=s[MIDX(rl,p0+8)], a3=s[MIDX(rl,p0+12)];
        dif4(a0,a1,a2,a3,w1,w2);
        s[MIDX(rl,p0)]=a0; s[MIDX(rl,p0+4)]=a1; s[MIDX(rl,p0+8)]=a2; s[MIDX(rl,p0+12)]=a3;
    }
    __syncthreads();

    // ---- register: fused(2,1) -> xG -> inverse fused(1,2) ----
    const float2* grow = Gb + (size_t)k1 * N2;
#pragma unroll
    for (int qq = 0; qq < 2; qq++) {
        int base = 4 * (rr + 32 * qq);
        float2 a0=s[MIDX(rl,base)], a1=s[MIDX(rl,base+1)], a2=s[MIDX(rl,base+2)], a3=s[MIDX(rl,base+3)];
        float2 s02 = cadd(a0,a2), d02 = csub(a0,a2);
        float2 s13 = cadd(a1,a3), d13 = csub(a1,a3);
        float2 b3 = make_float2(d13.y, -d13.x);
        float2 v0 = cadd(s02,s13), v1 = csub(s02,s13), v2 = cadd(d02,b3), v3 = csub(d02,b3);
        v0 = cmul(v0, grow[base]);   v1 = cmul(v1, grow[base+1]);
        v2 = cmul(v2, grow[base+2]); v3 = cmul(v3, grow[base+3]);
        float2 u0 = cadd(v0,v1), u1 = csub(v0,v1);
        float2 u2 = cadd(v2,v3), u3 = csub(v2,v3);
        s[MIDX(rl,base)]   = cadd(u0,u2);
        s[MIDX(rl,base+2)] = csub(u0,u2);
        s[MIDX(rl,base+1)] = make_float2(u1.x - u3.y, u1.y + u3.x);
        s[MIDX(rl,base+3)] = make_float2(u1.x + u3.y, u1.y - u3.x);
    }
    __syncthreads();

    // ---- inverse DIT ----
#pragma unroll
    for (int qq = 0; qq < 2; qq++) {
        int q = rr + 32 * qq, j = q & 3, g = q >> 2, p0 = g * 16 + j;
        float2 w2 = expif((float)j * (PI_F / 8.f)), w1 = cmul(w2, w2);
        float2 a0=s[MIDX(rl,p0)], a1=s[MIDX(rl,p0+4)], a2=s[MIDX(rl,p0+8)], a3=s[MIDX(rl,p0+12)];
        dit4i(a0,a1,a2,a3,w1,w2);
        s[MIDX(rl,p0)]=a0; s[MIDX(rl,p0+4)]=a1; s[MIDX(rl,p0+8)]=a2; s[MIDX(rl,p0+12)]=a3;
    }
    __syncthreads();
#pragma unroll
    for (int qq = 0; qq < 2; qq++) {
        int q = rr + 32 * qq, j = q & 15, g = q >> 4, p0 = g * 64 + j;
        float2 w2 = expif((float)j * (PI_F / 32.f)), w1 = cmul(w2, w2);
        float2 a0=s[MIDX(rl,p0)], a1=s[MIDX(rl,p0+16)], a2=s[MIDX(rl,p0+32)], a3=s[MIDX(rl,p0+48)];
        dit4i(a0,a1,a2,a3,w1,w2);
        s[MIDX(rl,p0)]=a0; s[MIDX(rl,p0+16)]=a1; s[MIDX(rl,p0+32)]=a2; s[MIDX(rl,p0+48)]=a3;
    }
    __syncthreads();
#pragma unroll
    for (int qq = 0; qq < 2; qq++) {
        int j = rr + 32 * qq;
        float2 w2 = expif((float)j * (PI_F / 128.f)), w1 = cmul(w2, w2);
        float2 a0=s[MIDX(rl,j)], a1=s[MIDX(rl,j+64)], a2=s[MIDX(rl,j+128)], a3=s[MIDX(rl,j+192)];
        dit4i(a0,a1,a2,a3,w1,w2);
        s[MIDX(rl,j)]=a0; s[MIDX(rl,j+64)]=a1; s[MIDX(rl,j+128)]=a2; s[MIDX(rl,j+192)]=a3;
    }
    __syncthreads();

    // conj big twiddle + store
#pragma unroll
    for (int i = 0; i < 8; i++) {
        int e = tid + 256 * i, rw = e >> 8, p = e & 255;
        int kk = (int)((rbase + rw) & (N1 - 1));
        float2 w = expif((float)(p * kk) * (2.f * PI_F / (float)N_FFT));
        buf[(rbase + rw) * N2 + p] = cmul(s[MIDX(rw, p)], w);
    }
}

// ---------------------------------------------------------------------------
// Inverse column FFT (512-pt DIT, brev load) over k1, scale, keep n1<256.
// 512 threads: r = tid>>4 in [0,32), c = tid&15.
// ---------------------------------------------------------------------------
__global__ __launch_bounds__(512, 4) void inv_cols(
    const float2* __restrict__ src, float* __restrict__ out)
{
    __shared__ float2 s[N1 * 16];
    const int tile = blockIdx.x, row = blockIdx.y, tid = threadIdx.x;
    const int n2base = tile * 16;
    const int c = tid & 15, r = tid >> 4;
    const float2* srow = src + (size_t)row * N_FFT;

#pragma unroll
    for (int i = 0; i < 16; i++) {
        int k1 = r + 32 * i;
        s[brev9(k1) * 16 + c] = srow[(size_t)k1 * N2 + n2base + c];
    }
    __syncthreads();

    // register octets: h=1 then fused (2,4), inverse constants
    const float2 w1c = make_float2(0.f, 1.f);     // conj(W_4^1) = i
    const float2 w2c = make_float2(R2_F, R2_F);   // conj(W_8^1)
    const float2 one = make_float2(1.f, 0.f);
#pragma unroll
    for (int o = 0; o < 2; o++) {
        int base = 8 * (r + 32 * o);
        float2 v[8];
#pragma unroll
        for (int m = 0; m < 8; m++) v[m] = s[(base + m) * 16 + c];
#pragma unroll
        for (int m = 0; m < 8; m += 2) {
            float2 a = v[m], b = v[m + 1];
            v[m] = cadd(a, b); v[m + 1] = csub(a, b);
        }
        dit4i(v[0], v[2], v[4], v[6], one, one);
        dit4i(v[1], v[3], v[5], v[7], w1c, w2c);
#pragma unroll
        for (int m = 0; m < 8; m++) s[(base + m) * 16 + c] = v[m];
    }
    __syncthreads();

    // fused (8,16)
#pragma unroll
    for (int qq = 0; qq < 4; qq++) {
        int q = r + 32 * qq, j = q & 7, g = q >> 3, p0 = g * 32 + j;
        float2 w2 = expif((float)j * (PI_F / 16.f)), w1 = cmul(w2, w2);
        float2 a0 = s[p0*16+c], a1 = s[(p0+8)*16+c], a2 = s[(p0+16)*16+c], a3 = s[(p0+24)*16+c];
        dit4i(a0, a1, a2, a3, w1, w2);
        s[p0*16+c] = a0; s[(p0+8)*16+c] = a1; s[(p0+16)*16+c] = a2; s[(p0+24)*16+c] = a3;
    }
    __syncthreads();
    // fused (32,64)
#pragma unroll
    for (int qq = 0; qq < 4; qq++) {
        int q = r + 32 * qq, j = q & 31, g = q >> 5, p0 = g * 128 + j;
        float2 w2 = expif((float)j * (PI_F / 64.f)), w1 = cmul(w2, w2);
        float2 a0 = s[p0*16+c], a1 = s[(p0+32)*16+c], a2 = s[(p0+64)*16+c], a3 = s[(p0+96)*16+c];
        dit4i(a0, a1, a2, a3, w1, w2);
        s[p0*16+c] = a0; s[(p0+32)*16+c] = a1; s[(p0+64)*16+c] = a2; s[(p0+96)*16+c] = a3;
    }
    __syncthreads();
    // fused (128,256)
#pragma unroll
    for (int qq = 0; qq < 4; qq++) {
        int j = r + 32 * qq;
        float2 w2 = expif((float)j * (PI_F / 256.f)), w1 = cmul(w2, w2);
        float2 a0 = s[j*16+c], a1 = s[(j+128)*16+c], a2 = s[(j+256)*16+c], a3 = s[(j+384)*16+c];
        dit4i(a0, a1, a2, a3, w1, w2);
        s[j*16+c] = a0; s[(j+128)*16+c] = a1; s[(j+256)*16+c] = a2; s[(j+384)*16+c] = a3;
    }
    __syncthreads();

    const float scale = 1.0f / (float)N_FFT;
    float* out0 = out + (size_t)(2 * row) * T_LEN;
    float* out1 = out + (size_t)(2 * row + 1) * T_LEN;
#pragma unroll
    for (int i = 0; i < 8; i++) {
        int p = r + 32 * i;                        // p < 256 only
        int n = p * N2 + n2base + c;
        float2 v = s[p * 16 + c];
        out0[n] = v.x * scale;
        out1[n] = v.y * scale;
    }
}

extern "C" void kernel_launch(void* const* d_in, const int* in_sizes, int n_in,
                              void* d_out, int out_size, void* d_ws, size_t ws_size,
                              hipStream_t stream) {
    const float* x    = (const float*)d_in[0];
    const float* filt = (const float*)d_in[1];
    float* out = (float*)d_out;

    float2* buf = (float2*)d_ws;                                               // 128 MB
    float2* G   = (float2*)((char*)d_ws + (size_t)CB * N_FFT * sizeof(float2)); // 1 MB

    fwd_cols<<<dim3(16, 1), 512, 0, stream>>>(filt, nullptr, 0LL, G);
    fwd_rows_g<<<N1 / 8, 256, 0, stream>>>(G);
    fwd_cols<<<dim3(16, CB), 512, 0, stream>>>(x, x + T_LEN, (long long)(2 * T_LEN), buf);
    mid_rows<<<(CB * N1) / 8, 256, 0, stream>>>(buf, G);
    inv_cols<<<dim3(16, CB), 512, 0, stream>>>(buf, out);
}

// Round 5
// 234.228 us; speedup vs baseline: 2.0101x; 1.0858x over previous
//
#include <hip/hip_runtime.h>

// Causal FIR conv via FFT (n_fft = 131072), four-step N = 512 x 256,
// transpose-free, batch-packed (2 real rows -> 1 complex row).
// v4b: fp16 global intermediate (halves sweep traffic, L3-resident),
// mid_rows at 512 thr + 16B-granular LDS padding + b128 register stage,
// fwd epilogue twiddles via power chain, vectorized h4 global I/O.
// (v4 fix: h2/h4 typedefs on __fp16 to match cvt_pkrtz's return type.)

#define N_FFT 131072
#define N1    512
#define N2    256
#define T_LEN 65536
#define CB    128
#define PI_F  3.14159265358979323846f
#define R2_F  0.70710678118654752f

typedef __attribute__((ext_vector_type(2))) __fp16 h2;
typedef __attribute__((ext_vector_type(4))) __fp16 h4;

__device__ inline int brev9(int x) { return (int)(__brev((unsigned)x) >> 23); }

__device__ inline float2 cadd(float2 a, float2 b){ return make_float2(a.x+b.x, a.y+b.y); }
__device__ inline float2 csub(float2 a, float2 b){ return make_float2(a.x-b.x, a.y-b.y); }
__device__ inline float2 cmul(float2 a, float2 b){ return make_float2(a.x*b.x-a.y*b.y, a.x*b.y+a.y*b.x); }
__device__ inline float2 expif(float a){ float s,c; __sincosf(a,&s,&c); return make_float2(c,s); }
__device__ inline h2 f2h(float2 v){ return __builtin_amdgcn_cvt_pkrtz(v.x, v.y); }

// Fused DIF double stage (h then h/2). quad (p0, p0+h/2, p0+h, p0+3h/2)
__device__ inline void dif4(float2&a0, float2&a1, float2&a2, float2&a3, float2 w1, float2 w2){
    float2 s02 = cadd(a0,a2), d02 = csub(a0,a2);
    float2 s13 = cadd(a1,a3), d13 = csub(a1,a3);
    float2 b2 = cmul(w1,d02);
    float2 t  = cmul(w1,d13);
    float2 b3 = make_float2(t.y, -t.x);          // -i*t
    a0 = cadd(s02,s13);
    a1 = cmul(w2, csub(s02,s13));
    a2 = cadd(b2,b3);
    a3 = cmul(w2, csub(b2,b3));
}

// Fused DIT double stage (h then 2h), inverse twiddles. quad (p0, p0+h, p0+2h, p0+3h)
__device__ inline void dit4i(float2&a0, float2&a1, float2&a2, float2&a3, float2 w1, float2 w2){
    float2 t1 = cmul(w1,a1), t3 = cmul(w1,a3);
    float2 u0 = cadd(a0,t1), u1 = csub(a0,t1);
    float2 u2 = cadd(a2,t3), u3 = csub(a2,t3);
    float2 s2 = cmul(w2,u2), s3 = cmul(w2,u3);
    a0 = cadd(u0,s2); a2 = csub(u0,s2);
    a1 = make_float2(u1.x - s3.y, u1.y + s3.x);  // u1 + i*s3
    a3 = make_float2(u1.x + s3.y, u1.y - s3.x);  // u1 - i*s3
}

// ---------------------------------------------------------------------------
// Forward column FFT (512-pt DIF) over n1, 16 columns/block, + big twiddle,
// store at natural k1 = brev9(p). Upper half (n1>=256) implicit zero.
// HALF=true -> fp16 output (data), HALF=false -> fp32 output (filter G).
// ---------------------------------------------------------------------------
template<bool HALF>
__global__ __launch_bounds__(512, 4) void fwd_cols(
    const float* __restrict__ re_base, const float* __restrict__ im_base,
    long long row_stride, void* __restrict__ dstv)
{
    __shared__ float2 s[N1 * 16];                 // 64 KB
    const int tile = blockIdx.x, row = blockIdx.y, tid = threadIdx.x;
    const int n2base = tile * 16;
    const float* rp = re_base + (long long)row * row_stride;
    const float* ip = im_base ? (im_base + (long long)row * row_stride) : nullptr;

    // coop load n1 in [0,256): pack (row0, row1) as (re, im)
    {
        const int cp = tid & 7, n1g = tid >> 3;   // n1g in [0,64)
#pragma unroll
        for (int i = 0; i < 4; i++) {
            int n1 = n1g + 64 * i;
            int g  = n1 * N2 + n2base + 2 * cp;
            float2 a = *(const float2*)(rp + g);
            float2 b = ip ? *(const float2*)(ip + g) : make_float2(0.f, 0.f);
            s[n1 * 16 + 2 * cp]     = make_float2(a.x, b.x);
            s[n1 * 16 + 2 * cp + 1] = make_float2(a.y, b.y);
        }
    }
    __syncthreads();

    const int c = tid & 15, r = tid >> 4;         // r in [0,32)

    // fused (256,128): p2,p3 inputs are zero (padding) -> read 2, write 4
#pragma unroll
    for (int qq = 0; qq < 4; qq++) {
        int j = r + 32 * qq;                      // 0..127
        float2 w1 = expif((float)j * (-PI_F / 256.f));
        float2 w2 = cmul(w1, w1);
        float2 a0 = s[j * 16 + c], a1 = s[(j + 128) * 16 + c];
        float2 b2 = cmul(w1, a0);
        float2 t  = cmul(w1, a1);
        float2 b3 = make_float2(t.y, -t.x);
        s[j * 16 + c]         = cadd(a0, a1);
        s[(j + 128) * 16 + c] = cmul(w2, csub(a0, a1));
        s[(j + 256) * 16 + c] = cadd(b2, b3);
        s[(j + 384) * 16 + c] = cmul(w2, csub(b2, b3));
    }
    __syncthreads();

    // fused (64,32)
#pragma unroll
    for (int qq = 0; qq < 4; qq++) {
        int q = r + 32 * qq, j = q & 31, g = q >> 5;
        int p0 = g * 128 + j;
        float2 w1 = expif((float)j * (-PI_F / 64.f));
        float2 w2 = cmul(w1, w1);
        float2 a0 = s[p0*16+c], a1 = s[(p0+32)*16+c], a2 = s[(p0+64)*16+c], a3 = s[(p0+96)*16+c];
        dif4(a0, a1, a2, a3, w1, w2);
        s[p0*16+c] = a0; s[(p0+32)*16+c] = a1; s[(p0+64)*16+c] = a2; s[(p0+96)*16+c] = a3;
    }
    __syncthreads();

    // fused (16,8)
#pragma unroll
    for (int qq = 0; qq < 4; qq++) {
        int q = r + 32 * qq, j = q & 7, g = q >> 3;
        int p0 = g * 32 + j;
        float2 w1 = expif((float)j * (-PI_F / 16.f));
        float2 w2 = cmul(w1, w1);
        float2 a0 = s[p0*16+c], a1 = s[(p0+8)*16+c], a2 = s[(p0+16)*16+c], a3 = s[(p0+24)*16+c];
        dif4(a0, a1, a2, a3, w1, w2);
        s[p0*16+c] = a0; s[(p0+8)*16+c] = a1; s[(p0+16)*16+c] = a2; s[(p0+24)*16+c] = a3;
    }
    __syncthreads();

    // register octets: fused (4,2) + h=1, big twiddle via power chain, store
    const int n2 = n2base + c;
    const float2 w1c = make_float2(R2_F, -R2_F);  // W_8^1
    const float2 w2c = make_float2(0.f, -1.f);    // W_4^1
    const float2 one = make_float2(1.f, 0.f);
    const float2 w64 = expif((float)n2 * (-PI_F / 1024.f));   // W_N^{64*n2}
#pragma unroll
    for (int o = 0; o < 2; o++) {
        int base = 8 * (r + 32 * o);
        float2 v[8];
#pragma unroll
        for (int m = 0; m < 8; m++) v[m] = s[(base + m) * 16 + c];
        dif4(v[0], v[2], v[4], v[6], one, one);
        dif4(v[1], v[3], v[5], v[7], w1c, w2c);
#pragma unroll
        for (int m = 0; m < 8; m += 2) {
            float2 a = v[m], b = v[m + 1];
            v[m] = cadd(a, b); v[m + 1] = csub(a, b);
        }
        // k1 = brev9(base+m) = Kb + 64*brev3(m); w = wK * w64^brev3(m)
        const int Kb = brev9(base);               // < 64
        float2 wK = expif((float)(n2 * Kb) * (-2.f * PI_F / (float)N_FFT));
        float2 pw[8];
        pw[0] = one;
#pragma unroll
        for (int k = 1; k < 8; k++) pw[k] = cmul(pw[k-1], w64);
        const int b3tab[8] = {0,4,2,6,1,5,3,7};
#pragma unroll
        for (int m = 0; m < 8; m++) {
            int b  = b3tab[m];
            int k1 = Kb + 64 * b;
            float2 w = cmul(wK, pw[b]);
            float2 rv = cmul(v[m], w);
            if (HALF) {
                h2* drow = (h2*)dstv + (size_t)row * N_FFT;
                drow[(size_t)k1 * N2 + n2] = f2h(rv);
            } else {
                float2* drow = (float2*)dstv + (size_t)row * N_FFT;
                drow[(size_t)k1 * N2 + n2] = rv;
            }
        }
    }
}

// ---------------------------------------------------------------------------
// LDS layout for row kernels: 16-B-granular padding (2 float2 per 16 points)
// ---------------------------------------------------------------------------
#define MROW 288
#define MIDX(rw, p) ((rw) * MROW + (p) + 2 * ((p) >> 4))

// ---------------------------------------------------------------------------
// Filter row FFTs: 256-pt forward DIF per k1-row (fp32), leave in brev order.
// ---------------------------------------------------------------------------
__global__ __launch_bounds__(256) void fwd_rows_g(float2* __restrict__ G)
{
    __shared__ float2 s[8 * MROW];
    const int tid = threadIdx.x;
    const long long rbase = (long long)blockIdx.x * 8;
#pragma unroll
    for (int i = 0; i < 8; i++) {
        int e = tid + 256 * i, rw = e >> 8, p = e & 255;
        s[MIDX(rw, p)] = G[(rbase + rw) * N2 + p];
    }
    __syncthreads();
    const int rl = tid >> 5, rr = tid & 31;
#pragma unroll
    for (int qq = 0; qq < 2; qq++) {
        int j = rr + 32 * qq;
        float2 w1 = expif((float)j * (-PI_F / 128.f)), w2 = cmul(w1, w1);
        float2 a0=s[MIDX(rl,j)], a1=s[MIDX(rl,j+64)], a2=s[MIDX(rl,j+128)], a3=s[MIDX(rl,j+192)];
        dif4(a0,a1,a2,a3,w1,w2);
        s[MIDX(rl,j)]=a0; s[MIDX(rl,j+64)]=a1; s[MIDX(rl,j+128)]=a2; s[MIDX(rl,j+192)]=a3;
    }
    __syncthreads();
#pragma unroll
    for (int qq = 0; qq < 2; qq++) {
        int q = rr + 32 * qq, j = q & 15, g = q >> 4, p0 = g * 64 + j;
        float2 w1 = expif((float)j * (-PI_F / 32.f)), w2 = cmul(w1, w1);
        float2 a0=s[MIDX(rl,p0)], a1=s[MIDX(rl,p0+16)], a2=s[MIDX(rl,p0+32)], a3=s[MIDX(rl,p0+48)];
        dif4(a0,a1,a2,a3,w1,w2);
        s[MIDX(rl,p0)]=a0; s[MIDX(rl,p0+16)]=a1; s[MIDX(rl,p0+32)]=a2; s[MIDX(rl,p0+48)]=a3;
    }
    __syncthreads();
#pragma unroll
    for (int qq = 0; qq < 2; qq++) {
        int q = rr + 32 * qq, j = q & 3, g = q >> 2, p0 = g * 16 + j;
        float2 w1 = expif((float)j * (-PI_F / 8.f)), w2 = cmul(w1, w1);
        float2 a0=s[MIDX(rl,p0)], a1=s[MIDX(rl,p0+4)], a2=s[MIDX(rl,p0+8)], a3=s[MIDX(rl,p0+12)];
        dif4(a0,a1,a2,a3,w1,w2);
        s[MIDX(rl,p0)]=a0; s[MIDX(rl,p0+4)]=a1; s[MIDX(rl,p0+8)]=a2; s[MIDX(rl,p0+12)]=a3;
    }
    __syncthreads();
#pragma unroll
    for (int qq = 0; qq < 2; qq++) {
        int base = 4 * (rr + 32 * qq);
        float2 a0=s[MIDX(rl,base)], a1=s[MIDX(rl,base+1)], a2=s[MIDX(rl,base+2)], a3=s[MIDX(rl,base+3)];
        float2 s02 = cadd(a0,a2), d02 = csub(a0,a2);
        float2 s13 = cadd(a1,a3), d13 = csub(a1,a3);
        float2 b3 = make_float2(d13.y, -d13.x);
        s[MIDX(rl,base)]   = cadd(s02,s13);
        s[MIDX(rl,base+1)] = csub(s02,s13);
        s[MIDX(rl,base+2)] = cadd(d02,b3);
        s[MIDX(rl,base+3)] = csub(d02,b3);
    }
    __syncthreads();
#pragma unroll
    for (int i = 0; i < 8; i++) {
        int e = tid + 256 * i, rw = e >> 8, p = e & 255;
        G[(rbase + rw) * N2 + p] = s[MIDX(rw, p)];
    }
}

// ---------------------------------------------------------------------------
// Fused mid: fwd row DIF -> x G(brev order) -> inv row DIT -> conj big twiddle
// 512 threads, 8 rows/block; fp16 global, fp32 LDS; b128 register stage.
// ---------------------------------------------------------------------------
__global__ __launch_bounds__(512) void mid_rows(
    h2* __restrict__ buf, const float2* __restrict__ Gb)
{
    __shared__ float4 s4[(8 * MROW) / 2];
    float2* s = (float2*)s4;
    const int tid = threadIdx.x;
    const long long rbase = (long long)blockIdx.x * 8;

    // load 2048 complex (h4 = 2 complex per lane-op)
#pragma unroll
    for (int i = 0; i < 2; i++) {
        int e = tid + 512 * i;                     // 0..1023
        int rw = e >> 7, pp = (e & 127) * 2;
        h4 v = *((const h4*)(buf + (rbase + rw) * N2 + pp));
        s4[MIDX(rw, pp) >> 1] = make_float4((float)v.x, (float)v.y, (float)v.z, (float)v.w);
    }
    __syncthreads();

    const int rl = tid >> 6, rr = tid & 63;
    const int k1 = (int)((rbase + rl) & (N1 - 1));

    // ---- forward DIF (128,64) ----
    {
        int j = rr;
        float2 w1 = expif((float)j * (-PI_F / 128.f)), w2 = cmul(w1, w1);
        float2 a0=s[MIDX(rl,j)], a1=s[MIDX(rl,j+64)], a2=s[MIDX(rl,j+128)], a3=s[MIDX(rl,j+192)];
        dif4(a0,a1,a2,a3,w1,w2);
        s[MIDX(rl,j)]=a0; s[MIDX(rl,j+64)]=a1; s[MIDX(rl,j+128)]=a2; s[MIDX(rl,j+192)]=a3;
    }
    __syncthreads();
    // ---- (32,16) ----
    {
        int j = rr & 15, g = rr >> 4, p0 = g * 64 + j;
        float2 w1 = expif((float)j * (-PI_F / 32.f)), w2 = cmul(w1, w1);
        float2 a0=s[MIDX(rl,p0)], a1=s[MIDX(rl,p0+16)], a2=s[MIDX(rl,p0+32)], a3=s[MIDX(rl,p0+48)];
        dif4(a0,a1,a2,a3,w1,w2);
        s[MIDX(rl,p0)]=a0; s[MIDX(rl,p0+16)]=a1; s[MIDX(rl,p0+32)]=a2; s[MIDX(rl,p0+48)]=a3;
    }
    __syncthreads();
    // ---- (8,4) ----
    {
        int j = rr & 3, g = rr >> 2, p0 = g * 16 + j;
        float2 w1 = expif((float)j * (-PI_F / 8.f)), w2 = cmul(w1, w1);
        float2 a0=s[MIDX(rl,p0)], a1=s[MIDX(rl,p0+4)], a2=s[MIDX(rl,p0+8)], a3=s[MIDX(rl,p0+12)];
        dif4(a0,a1,a2,a3,w1,w2);
        s[MIDX(rl,p0)]=a0; s[MIDX(rl,p0+4)]=a1; s[MIDX(rl,p0+8)]=a2; s[MIDX(rl,p0+12)]=a3;
    }
    __syncthreads();

    // ---- register: fused(2,1) -> xG -> inverse fused(1,2), b128 I/O ----
    {
        int base = 4 * rr;
        int si = MIDX(rl, base) >> 1;
        float4 q01 = s4[si], q23 = s4[si + 1];
        float2 a0 = make_float2(q01.x, q01.y), a1 = make_float2(q01.z, q01.w);
        float2 a2 = make_float2(q23.x, q23.y), a3 = make_float2(q23.z, q23.w);
        float2 s02 = cadd(a0,a2), d02 = csub(a0,a2);
        float2 s13 = cadd(a1,a3), d13 = csub(a1,a3);
        float2 b3 = make_float2(d13.y, -d13.x);
        float2 v0 = cadd(s02,s13), v1 = csub(s02,s13), v2 = cadd(d02,b3), v3 = csub(d02,b3);
        const float4* g4 = (const float4*)(Gb + (size_t)k1 * N2);
        float4 g01 = g4[base >> 1], g23 = g4[(base >> 1) + 1];
        v0 = cmul(v0, make_float2(g01.x, g01.y));
        v1 = cmul(v1, make_float2(g01.z, g01.w));
        v2 = cmul(v2, make_float2(g23.x, g23.y));
        v3 = cmul(v3, make_float2(g23.z, g23.w));
        float2 u0 = cadd(v0,v1), u1 = csub(v0,v1);
        float2 u2 = cadd(v2,v3), u3 = csub(v2,v3);
        float2 r0 = cadd(u0,u2), r2 = csub(u0,u2);
        float2 r1 = make_float2(u1.x - u3.y, u1.y + u3.x);
        float2 r3 = make_float2(u1.x + u3.y, u1.y - u3.x);
        s4[si]     = make_float4(r0.x, r0.y, r1.x, r1.y);
        s4[si + 1] = make_float4(r2.x, r2.y, r3.x, r3.y);
    }
    __syncthreads();

    // ---- inverse DIT (4,8) ----
    {
        int j = rr & 3, g = rr >> 2, p0 = g * 16 + j;
        float2 w2 = expif((float)j * (PI_F / 8.f)), w1 = cmul(w2, w2);
        float2 a0=s[MIDX(rl,p0)], a1=s[MIDX(rl,p0+4)], a2=s[MIDX(rl,p0+8)], a3=s[MIDX(rl,p0+12)];
        dit4i(a0,a1,a2,a3,w1,w2);
        s[MIDX(rl,p0)]=a0; s[MIDX(rl,p0+4)]=a1; s[MIDX(rl,p0+8)]=a2; s[MIDX(rl,p0+12)]=a3;
    }
    __syncthreads();
    // ---- (16,32) ----
    {
        int j = rr & 15, g = rr >> 4, p0 = g * 64 + j;
        float2 w2 = expif((float)j * (PI_F / 32.f)), w1 = cmul(w2, w2);
        float2 a0=s[MIDX(rl,p0)], a1=s[MIDX(rl,p0+16)], a2=s[MIDX(rl,p0+32)], a3=s[MIDX(rl,p0+48)];
        dit4i(a0,a1,a2,a3,w1,w2);
        s[MIDX(rl,p0)]=a0; s[MIDX(rl,p0+16)]=a1; s[MIDX(rl,p0+32)]=a2; s[MIDX(rl,p0+48)]=a3;
    }
    __syncthreads();
    // ---- (64,128) ----
    {
        int j = rr;
        float2 w2 = expif((float)j * (PI_F / 128.f)), w1 = cmul(w2, w2);
        float2 a0=s[MIDX(rl,j)], a1=s[MIDX(rl,j+64)], a2=s[MIDX(rl,j+128)], a3=s[MIDX(rl,j+192)];
        dit4i(a0,a1,a2,a3,w1,w2);
        s[MIDX(rl,j)]=a0; s[MIDX(rl,j+64)]=a1; s[MIDX(rl,j+128)]=a2; s[MIDX(rl,j+192)]=a3;
    }
    __syncthreads();

    // conj big twiddle + h4 store
#pragma unroll
    for (int i = 0; i < 2; i++) {
        int e = tid + 512 * i;
        int rw = e >> 7, pp = (e & 127) * 2;
        int kk = (int)((rbase + rw) & (N1 - 1));
        float4 q = s4[MIDX(rw, pp) >> 1];
        float2 wA = expif((float)(pp * kk) * (2.f * PI_F / (float)N_FFT));
        float2 wB = expif((float)((pp + 1) * kk) * (2.f * PI_F / (float)N_FFT));
        float2 rA = cmul(make_float2(q.x, q.y), wA);
        float2 rB = cmul(make_float2(q.z, q.w), wB);
        h2 ha = f2h(rA), hb = f2h(rB);
        h4 o; o.x = ha.x; o.y = ha.y; o.z = hb.x; o.w = hb.y;
        *((h4*)(buf + (rbase + rw) * N2 + pp)) = o;
    }
}

// ---------------------------------------------------------------------------
// Inverse column FFT (512-pt DIT, brev load) over k1, scale, keep n1<256.
// ---------------------------------------------------------------------------
__global__ __launch_bounds__(512, 4) void inv_cols(
    const h2* __restrict__ src, float* __restrict__ out)
{
    __shared__ float4 s4[N1 * 16 / 2];            // 64 KB
    float2* s = (float2*)s4;
    const int tile = blockIdx.x, row = blockIdx.y, tid = threadIdx.x;
    const int n2base = tile * 16;
    const h2* srow = src + (size_t)row * N_FFT;
    const int cp = tid & 7, r8 = tid >> 3;        // r8 in [0,64)

#pragma unroll
    for (int i = 0; i < 8; i++) {
        int k1 = r8 + 64 * i;
        h4 v = *((const h4*)(srow + (size_t)k1 * N2 + n2base + 2 * cp));
        int p = brev9(k1);
        s4[p * 8 + cp] = make_float4((float)v.x, (float)v.y, (float)v.z, (float)v.w);
    }
    __syncthreads();

    const int c = tid & 15, r = tid >> 4;         // r in [0,32)

    // register octets: h=1 then fused (2,4), inverse constants
    const float2 w1c = make_float2(0.f, 1.f);     // conj(W_4^1) = i
    const float2 w2c = make_float2(R2_F, R2_F);   // conj(W_8^1)
    const float2 one = make_float2(1.f, 0.f);
#pragma unroll
    for (int o = 0; o < 2; o++) {
        int base = 8 * (r + 32 * o);
        float2 v[8];
#pragma unroll
        for (int m = 0; m < 8; m++) v[m] = s[(base + m) * 16 + c];
#pragma unroll
        for (int m = 0; m < 8; m += 2) {
            float2 a = v[m], b = v[m + 1];
            v[m] = cadd(a, b); v[m + 1] = csub(a, b);
        }
        dit4i(v[0], v[2], v[4], v[6], one, one);
        dit4i(v[1], v[3], v[5], v[7], w1c, w2c);
#pragma unroll
        for (int m = 0; m < 8; m++) s[(base + m) * 16 + c] = v[m];
    }
    __syncthreads();

    // fused (8,16)
#pragma unroll
    for (int qq = 0; qq < 4; qq++) {
        int q = r + 32 * qq, j = q & 7, g = q >> 3, p0 = g * 32 + j;
        float2 w2 = expif((float)j * (PI_F / 16.f)), w1 = cmul(w2, w2);
        float2 a0 = s[p0*16+c], a1 = s[(p0+8)*16+c], a2 = s[(p0+16)*16+c], a3 = s[(p0+24)*16+c];
        dit4i(a0, a1, a2, a3, w1, w2);
        s[p0*16+c] = a0; s[(p0+8)*16+c] = a1; s[(p0+16)*16+c] = a2; s[(p0+24)*16+c] = a3;
    }
    __syncthreads();
    // fused (32,64)
#pragma unroll
    for (int qq = 0; qq < 4; qq++) {
        int q = r + 32 * qq, j = q & 31, g = q >> 5, p0 = g * 128 + j;
        float2 w2 = expif((float)j * (PI_F / 64.f)), w1 = cmul(w2, w2);
        float2 a0 = s[p0*16+c], a1 = s[(p0+32)*16+c], a2 = s[(p0+64)*16+c], a3 = s[(p0+96)*16+c];
        dit4i(a0, a1, a2, a3, w1, w2);
        s[p0*16+c] = a0; s[(p0+32)*16+c] = a1; s[(p0+64)*16+c] = a2; s[(p0+96)*16+c] = a3;
    }
    __syncthreads();
    // fused (128,256)
#pragma unroll
    for (int qq = 0; qq < 4; qq++) {
        int j = r + 32 * qq;
        float2 w2 = expif((float)j * (PI_F / 256.f)), w1 = cmul(w2, w2);
        float2 a0 = s[j*16+c], a1 = s[(j+128)*16+c], a2 = s[(j+256)*16+c], a3 = s[(j+384)*16+c];
        dit4i(a0, a1, a2, a3, w1, w2);
        s[j*16+c] = a0; s[(j+128)*16+c] = a1; s[(j+256)*16+c] = a2; s[(j+384)*16+c] = a3;
    }
    __syncthreads();

    const float scale = 1.0f / (float)N_FFT;
    float* out0 = out + (size_t)(2 * row) * T_LEN;
    float* out1 = out + (size_t)(2 * row + 1) * T_LEN;
#pragma unroll
    for (int i = 0; i < 4; i++) {
        int p = r8 + 64 * i;                      // p < 256
        float4 q = s4[p * 8 + cp];
        int n = p * N2 + n2base + 2 * cp;
        *(float2*)(out0 + n) = make_float2(q.x * scale, q.z * scale);
        *(float2*)(out1 + n) = make_float2(q.y * scale, q.w * scale);
    }
}

extern "C" void kernel_launch(void* const* d_in, const int* in_sizes, int n_in,
                              void* d_out, int out_size, void* d_ws, size_t ws_size,
                              hipStream_t stream) {
    const float* x    = (const float*)d_in[0];
    const float* filt = (const float*)d_in[1];
    float* out = (float*)d_out;

    h2* buf = (h2*)d_ws;                                                        // 67 MB
    float2* G = (float2*)((char*)d_ws + (size_t)CB * N_FFT * sizeof(h2));       // 1 MB

    fwd_cols<false><<<dim3(16, 1), 512, 0, stream>>>(filt, nullptr, 0LL, (void*)G);
    fwd_rows_g<<<N1 / 8, 256, 0, stream>>>(G);
    fwd_cols<true><<<dim3(16, CB), 512, 0, stream>>>(x, x + T_LEN, (long long)(2 * T_LEN), (void*)buf);
    mid_rows<<<(CB * N1) / 8, 512, 0, stream>>>(buf, G);
    inv_cols<<<dim3(16, CB), 512, 0, stream>>>(buf, out);
}

// Round 6
// 231.497 us; speedup vs baseline: 2.0338x; 1.0118x over previous
//
#include <hip/hip_runtime.h>

// Causal FIR conv via FFT (n_fft = 131072), four-step N = 512 x 256,
// transpose-free, batch-packed (2 real rows -> 1 complex row).
// v5: VALU-diet. mid_rows: folded LDS addressing (const ds offsets),
// twiddles by squaring chain (1 sincos instead of 6), h8 16B global I/O,
// chained epilogue twiddles. fwd/inv cols: hoisted qq-invariant stage
// twiddles, constant-step chains for the qq-varying stage.

#define N_FFT 131072
#define N1    512
#define N2    256
#define T_LEN 65536
#define CB    128
#define PI_F  3.14159265358979323846f
#define R2_F  0.70710678118654752f

typedef __attribute__((ext_vector_type(2))) __fp16 h2;
typedef __attribute__((ext_vector_type(4))) __fp16 h4;
typedef __attribute__((ext_vector_type(8))) __fp16 h8;

__device__ inline int brev9(int x) { return (int)(__brev((unsigned)x) >> 23); }

__device__ inline float2 cadd(float2 a, float2 b){ return make_float2(a.x+b.x, a.y+b.y); }
__device__ inline float2 csub(float2 a, float2 b){ return make_float2(a.x-b.x, a.y-b.y); }
__device__ inline float2 cmul(float2 a, float2 b){ return make_float2(a.x*b.x-a.y*b.y, a.x*b.y+a.y*b.x); }
__device__ inline float2 csq(float2 a){ return make_float2(a.x*a.x-a.y*a.y, 2.f*a.x*a.y); }
__device__ inline float2 conjf(float2 a){ return make_float2(a.x, -a.y); }
__device__ inline float2 expif(float a){ float s,c; __sincosf(a,&s,&c); return make_float2(c,s); }
__device__ inline h2 f2h(float2 v){ return __builtin_amdgcn_cvt_pkrtz(v.x, v.y); }
// multiply by i^g (g mod 4), branchless (cndmask)
__device__ inline float2 mul_ipow(float2 a, int g){
    float2 b = (g & 1) ? make_float2(-a.y, a.x) : a;
    return (g & 2) ? make_float2(-b.x, -b.y) : b;
}

// Fused DIF double stage (h then h/2). quad (p0, p0+h/2, p0+h, p0+3h/2)
__device__ inline void dif4(float2&a0, float2&a1, float2&a2, float2&a3, float2 w1, float2 w2){
    float2 s02 = cadd(a0,a2), d02 = csub(a0,a2);
    float2 s13 = cadd(a1,a3), d13 = csub(a1,a3);
    float2 b2 = cmul(w1,d02);
    float2 t  = cmul(w1,d13);
    float2 b3 = make_float2(t.y, -t.x);          // -i*t
    a0 = cadd(s02,s13);
    a1 = cmul(w2, csub(s02,s13));
    a2 = cadd(b2,b3);
    a3 = cmul(w2, csub(b2,b3));
}

// Fused DIT double stage (h then 2h), inverse twiddles. quad (p0, p0+h, p0+2h, p0+3h)
__device__ inline void dit4i(float2&a0, float2&a1, float2&a2, float2&a3, float2 w1, float2 w2){
    float2 t1 = cmul(w1,a1), t3 = cmul(w1,a3);
    float2 u0 = cadd(a0,t1), u1 = csub(a0,t1);
    float2 u2 = cadd(a2,t3), u3 = csub(a2,t3);
    float2 s2 = cmul(w2,u2), s3 = cmul(w2,u3);
    a0 = cadd(u0,s2); a2 = csub(u0,s2);
    a1 = make_float2(u1.x - s3.y, u1.y + s3.x);  // u1 + i*s3
    a3 = make_float2(u1.x + s3.y, u1.y - s3.x);  // u1 - i*s3
}

// ---------------------------------------------------------------------------
// Forward column FFT (512-pt DIF) over n1, 16 columns/block, + big twiddle,
// store at natural k1 = brev9(p). Upper half (n1>=256) implicit zero.
// ---------------------------------------------------------------------------
template<bool HALF>
__global__ __launch_bounds__(512, 4) void fwd_cols(
    const float* __restrict__ re_base, const float* __restrict__ im_base,
    long long row_stride, void* __restrict__ dstv)
{
    __shared__ float2 s[N1 * 16];                 // 64 KB
    const int tile = blockIdx.x, row = blockIdx.y, tid = threadIdx.x;
    const int n2base = tile * 16;
    const float* rp = re_base + (long long)row * row_stride;
    const float* ip = im_base ? (im_base + (long long)row * row_stride) : nullptr;

    {
        const int cp = tid & 7, n1g = tid >> 3;
#pragma unroll
        for (int i = 0; i < 4; i++) {
            int n1 = n1g + 64 * i;
            int g  = n1 * N2 + n2base + 2 * cp;
            float2 a = *(const float2*)(rp + g);
            float2 b = ip ? *(const float2*)(ip + g) : make_float2(0.f, 0.f);
            s[n1 * 16 + 2 * cp]     = make_float2(a.x, b.x);
            s[n1 * 16 + 2 * cp + 1] = make_float2(a.y, b.y);
        }
    }
    __syncthreads();

    const int c = tid & 15, r = tid >> 4;         // r in [0,32)

    // fused (256,128): chained twiddle, step = W_512^{32} = e^{-i pi/8}
    {
        float2 w1 = expif((float)r * (-PI_F / 256.f));
        const float2 stp = make_float2(0.92387953251f, -0.38268343236f);
#pragma unroll
        for (int qq = 0; qq < 4; qq++) {
            int j = r + 32 * qq;
            float2 w2 = csq(w1);
            float2 a0 = s[j * 16 + c], a1 = s[(j + 128) * 16 + c];
            float2 b2 = cmul(w1, a0);
            float2 t  = cmul(w1, a1);
            float2 b3 = make_float2(t.y, -t.x);
            s[j * 16 + c]         = cadd(a0, a1);
            s[(j + 128) * 16 + c] = cmul(w2, csub(a0, a1));
            s[(j + 256) * 16 + c] = cadd(b2, b3);
            s[(j + 384) * 16 + c] = cmul(w2, csub(b2, b3));
            w1 = cmul(w1, stp);
        }
    }
    __syncthreads();

    // fused (64,32): j = r invariant across qq
    {
        float2 w1 = expif((float)r * (-PI_F / 64.f));
        float2 w2 = csq(w1);
#pragma unroll
        for (int qq = 0; qq < 4; qq++) {
            int p0 = qq * 128 + r;
            float2 a0 = s[p0*16+c], a1 = s[(p0+32)*16+c], a2 = s[(p0+64)*16+c], a3 = s[(p0+96)*16+c];
            dif4(a0, a1, a2, a3, w1, w2);
            s[p0*16+c] = a0; s[(p0+32)*16+c] = a1; s[(p0+64)*16+c] = a2; s[(p0+96)*16+c] = a3;
        }
    }
    __syncthreads();

    // fused (16,8): j = r&7 invariant across qq
    {
        float2 w1 = expif((float)(r & 7) * (-PI_F / 16.f));
        float2 w2 = csq(w1);
#pragma unroll
        for (int qq = 0; qq < 4; qq++) {
            int g = (r >> 3) + 4 * qq;
            int p0 = g * 32 + (r & 7);
            float2 a0 = s[p0*16+c], a1 = s[(p0+8)*16+c], a2 = s[(p0+16)*16+c], a3 = s[(p0+24)*16+c];
            dif4(a0, a1, a2, a3, w1, w2);
            s[p0*16+c] = a0; s[(p0+8)*16+c] = a1; s[(p0+16)*16+c] = a2; s[(p0+24)*16+c] = a3;
        }
    }
    __syncthreads();

    // register octets: fused (4,2) + h=1, big twiddle via power chain, store
    const int n2 = n2base + c;
    const float2 w1c = make_float2(R2_F, -R2_F);  // W_8^1
    const float2 w2c = make_float2(0.f, -1.f);    // W_4^1
    const float2 one = make_float2(1.f, 0.f);
    const float2 w64 = expif((float)n2 * (-PI_F / 1024.f));   // W_N^{64*n2}
#pragma unroll
    for (int o = 0; o < 2; o++) {
        int base = 8 * (r + 32 * o);
        float2 v[8];
#pragma unroll
        for (int m = 0; m < 8; m++) v[m] = s[(base + m) * 16 + c];
        dif4(v[0], v[2], v[4], v[6], one, one);
        dif4(v[1], v[3], v[5], v[7], w1c, w2c);
#pragma unroll
        for (int m = 0; m < 8; m += 2) {
            float2 a = v[m], b = v[m + 1];
            v[m] = cadd(a, b); v[m + 1] = csub(a, b);
        }
        const int Kb = brev9(base);               // < 64
        float2 wK = expif((float)(n2 * Kb) * (-2.f * PI_F / (float)N_FFT));
        float2 pw[8];
        pw[0] = one;
#pragma unroll
        for (int k = 1; k < 8; k++) pw[k] = cmul(pw[k-1], w64);
        const int b3tab[8] = {0,4,2,6,1,5,3,7};
#pragma unroll
        for (int m = 0; m < 8; m++) {
            int b  = b3tab[m];
            int k1 = Kb + 64 * b;
            float2 w = cmul(wK, pw[b]);
            float2 rv = cmul(v[m], w);
            if (HALF) {
                h2* drow = (h2*)dstv + (size_t)row * N_FFT;
                drow[(size_t)k1 * N2 + n2] = f2h(rv);
            } else {
                float2* drow = (float2*)dstv + (size_t)row * N_FFT;
                drow[(size_t)k1 * N2 + n2] = rv;
            }
        }
    }
}

// ---------------------------------------------------------------------------
// LDS layout for row kernels: 16-B-granular padding (2 float2 per 16 points)
// ---------------------------------------------------------------------------
#define MROW 288
#define MIDX(rw, p) ((rw) * MROW + (p) + 2 * ((p) >> 4))

// ---------------------------------------------------------------------------
// Filter row FFTs: 256-pt forward DIF per k1-row (fp32), leave in brev order.
// ---------------------------------------------------------------------------
__global__ __launch_bounds__(256) void fwd_rows_g(float2* __restrict__ G)
{
    __shared__ float2 s[8 * MROW];
    const int tid = threadIdx.x;
    const long long rbase = (long long)blockIdx.x * 8;
#pragma unroll
    for (int i = 0; i < 8; i++) {
        int e = tid + 256 * i, rw = e >> 8, p = e & 255;
        s[MIDX(rw, p)] = G[(rbase + rw) * N2 + p];
    }
    __syncthreads();
    const int rl = tid >> 5, rr = tid & 31;
#pragma unroll
    for (int qq = 0; qq < 2; qq++) {
        int j = rr + 32 * qq;
        float2 w1 = expif((float)j * (-PI_F / 128.f)), w2 = csq(w1);
        float2 a0=s[MIDX(rl,j)], a1=s[MIDX(rl,j+64)], a2=s[MIDX(rl,j+128)], a3=s[MIDX(rl,j+192)];
        dif4(a0,a1,a2,a3,w1,w2);
        s[MIDX(rl,j)]=a0; s[MIDX(rl,j+64)]=a1; s[MIDX(rl,j+128)]=a2; s[MIDX(rl,j+192)]=a3;
    }
    __syncthreads();
#pragma unroll
    for (int qq = 0; qq < 2; qq++) {
        int q = rr + 32 * qq, j = q & 15, g = q >> 4, p0 = g * 64 + j;
        float2 w1 = expif((float)j * (-PI_F / 32.f)), w2 = csq(w1);
        float2 a0=s[MIDX(rl,p0)], a1=s[MIDX(rl,p0+16)], a2=s[MIDX(rl,p0+32)], a3=s[MIDX(rl,p0+48)];
        dif4(a0,a1,a2,a3,w1,w2);
        s[MIDX(rl,p0)]=a0; s[MIDX(rl,p0+16)]=a1; s[MIDX(rl,p0+32)]=a2; s[MIDX(rl,p0+48)]=a3;
    }
    __syncthreads();
#pragma unroll
    for (int qq = 0; qq < 2; qq++) {
        int q = rr + 32 * qq, j = q & 3, g = q >> 2, p0 = g * 16 + j;
        float2 w1 = expif((float)j * (-PI_F / 8.f)), w2 = csq(w1);
        float2 a0=s[MIDX(rl,p0)], a1=s[MIDX(rl,p0+4)], a2=s[MIDX(rl,p0+8)], a3=s[MIDX(rl,p0+12)];
        dif4(a0,a1,a2,a3,w1,w2);
        s[MIDX(rl,p0)]=a0; s[MIDX(rl,p0+4)]=a1; s[MIDX(rl,p0+8)]=a2; s[MIDX(rl,p0+12)]=a3;
    }
    __syncthreads();
#pragma unroll
    for (int qq = 0; qq < 2; qq++) {
        int base = 4 * (rr + 32 * qq);
        float2 a0=s[MIDX(rl,base)], a1=s[MIDX(rl,base+1)], a2=s[MIDX(rl,base+2)], a3=s[MIDX(rl,base+3)];
        float2 s02 = cadd(a0,a2), d02 = csub(a0,a2);
        float2 s13 = cadd(a1,a3), d13 = csub(a1,a3);
        float2 b3 = make_float2(d13.y, -d13.x);
        s[MIDX(rl,base)]   = cadd(s02,s13);
        s[MIDX(rl,base+1)] = csub(s02,s13);
        s[MIDX(rl,base+2)] = cadd(d02,b3);
        s[MIDX(rl,base+3)] = csub(d02,b3);
    }
    __syncthreads();
#pragma unroll
    for (int i = 0; i < 8; i++) {
        int e = tid + 256 * i, rw = e >> 8, p = e & 255;
        G[(rbase + rw) * N2 + p] = s[MIDX(rw, p)];
    }
}

// ---------------------------------------------------------------------------
// Fused mid: fwd row DIF -> x G(brev order) -> inv row DIT -> conj big twiddle
// 512 threads, 8 rows/block; fp16 global (h8 16B I/O), fp32 LDS.
// Folded addresses (const ds offsets), twiddles from one sincos via squaring.
// ---------------------------------------------------------------------------
__global__ __launch_bounds__(512) void mid_rows(
    h2* __restrict__ buf, const float2* __restrict__ Gb)
{
    __shared__ float4 s4[(8 * MROW) / 2];
    float2* s = (float2*)s4;
    const int tid = threadIdx.x;
    const long long rbase = (long long)blockIdx.x * 8;

    const int rl = tid >> 6, rr = tid & 63;
    const int k1 = (int)((rbase + rl) & (N1 - 1));

    // folded LDS bases (float2 units); deltas are compile-time constants
    const int rB = rl * MROW;
    const int b1 = rB + rr + ((rr >> 4) << 1);            // stage (128,64): +72
    const int b2 = rB + 72 * (rr >> 4) + (rr & 15);       // stage (32,16):  +18
    const int b3 = rB + 18 * (rr >> 2) + (rr & 3);        // stage (8,4):    +4
    const int si = 144 * rl + 2 * rr + (rr >> 2);         // float4 units (4 consec pts)

    // twiddle chain: u0 = W256^rr, u1 = W256^{4rr}, u2 = W256^{16rr}
    const float2 u0 = expif((float)rr * (-PI_F / 128.f));
    const float2 u1 = csq(csq(u0));
    const float2 u2 = csq(csq(u1));
    const float2 f2 = mul_ipow(u1, rr >> 4);              // W64^{rr&15}
    const float2 f3 = mul_ipow(u2, rr >> 2);              // W16^{rr&3}

    // ---- load: one h8 (4 complex) per thread ----
    {
        h8 v = *((const h8*)(buf + ((rbase + rl) * N2 + 4 * rr)));
        s4[si]     = make_float4((float)v[0], (float)v[1], (float)v[2], (float)v[3]);
        s4[si + 1] = make_float4((float)v[4], (float)v[5], (float)v[6], (float)v[7]);
    }
    __syncthreads();

    // ---- forward DIF (128,64) ----
    {
        float2 w2 = csq(u0);
        float2 a0=s[b1], a1=s[b1+72], a2=s[b1+144], a3=s[b1+216];
        dif4(a0,a1,a2,a3,u0,w2);
        s[b1]=a0; s[b1+72]=a1; s[b1+144]=a2; s[b1+216]=a3;
    }
    __syncthreads();
    // ---- (32,16) ----
    {
        float2 w2 = csq(f2);
        float2 a0=s[b2], a1=s[b2+18], a2=s[b2+36], a3=s[b2+54];
        dif4(a0,a1,a2,a3,f2,w2);
        s[b2]=a0; s[b2+18]=a1; s[b2+36]=a2; s[b2+54]=a3;
    }
    __syncthreads();
    // ---- (8,4) ----
    {
        float2 w2 = csq(f3);
        float2 a0=s[b3], a1=s[b3+4], a2=s[b3+8], a3=s[b3+12];
        dif4(a0,a1,a2,a3,f3,w2);
        s[b3]=a0; s[b3+4]=a1; s[b3+8]=a2; s[b3+12]=a3;
    }
    __syncthreads();

    // ---- register: fused(2,1) -> xG -> inverse fused(1,2), b128 I/O ----
    {
        int base = 4 * rr;
        float4 q01 = s4[si], q23 = s4[si + 1];
        float2 a0 = make_float2(q01.x, q01.y), a1 = make_float2(q01.z, q01.w);
        float2 a2 = make_float2(q23.x, q23.y), a3 = make_float2(q23.z, q23.w);
        float2 s02 = cadd(a0,a2), d02 = csub(a0,a2);
        float2 s13 = cadd(a1,a3), d13 = csub(a1,a3);
        float2 b3v = make_float2(d13.y, -d13.x);
        float2 v0 = cadd(s02,s13), v1 = csub(s02,s13), v2 = cadd(d02,b3v), v3 = csub(d02,b3v);
        const float4* g4 = (const float4*)(Gb + (size_t)k1 * N2);
        float4 g01 = g4[base >> 1], g23 = g4[(base >> 1) + 1];
        v0 = cmul(v0, make_float2(g01.x, g01.y));
        v1 = cmul(v1, make_float2(g01.z, g01.w));
        v2 = cmul(v2, make_float2(g23.x, g23.y));
        v3 = cmul(v3, make_float2(g23.z, g23.w));
        float2 u0v = cadd(v0,v1), u1v = csub(v0,v1);
        float2 u2v = cadd(v2,v3), u3v = csub(v2,v3);
        float2 r0 = cadd(u0v,u2v), r2 = csub(u0v,u2v);
        float2 r1 = make_float2(u1v.x - u3v.y, u1v.y + u3v.x);
        float2 r3 = make_float2(u1v.x + u3v.y, u1v.y - u3v.x);
        s4[si]     = make_float4(r0.x, r0.y, r1.x, r1.y);
        s4[si + 1] = make_float4(r2.x, r2.y, r3.x, r3.y);
    }
    __syncthreads();

    // ---- inverse DIT (4,8): w2 = conj(f3) ----
    {
        float2 w2 = conjf(f3), w1 = csq(w2);
        float2 a0=s[b3], a1=s[b3+4], a2=s[b3+8], a3=s[b3+12];
        dit4i(a0,a1,a2,a3,w1,w2);
        s[b3]=a0; s[b3+4]=a1; s[b3+8]=a2; s[b3+12]=a3;
    }
    __syncthreads();
    // ---- (16,32): w2 = conj(f2) ----
    {
        float2 w2 = conjf(f2), w1 = csq(w2);
        float2 a0=s[b2], a1=s[b2+18], a2=s[b2+36], a3=s[b2+54];
        dit4i(a0,a1,a2,a3,w1,w2);
        s[b2]=a0; s[b2+18]=a1; s[b2+36]=a2; s[b2+54]=a3;
    }
    __syncthreads();
    // ---- (64,128): w2 = conj(u0) ----
    {
        float2 w2 = conjf(u0), w1 = csq(w2);
        float2 a0=s[b1], a1=s[b1+72], a2=s[b1+144], a3=s[b1+216];
        dit4i(a0,a1,a2,a3,w1,w2);
        s[b1]=a0; s[b1+72]=a1; s[b1+144]=a2; s[b1+216]=a3;
    }
    __syncthreads();

    // ---- conj big twiddle, chained (2 sincos + 3 cmul per 4 pts), h8 store ----
    {
        const int pp0 = 4 * rr;
        const float th = 2.f * PI_F / (float)N_FFT;
        float2 w = expif((float)(pp0 * k1) * th);
        float2 stp = expif((float)k1 * th);
        float4 q01 = s4[si], q23 = s4[si + 1];
        float2 r0 = cmul(make_float2(q01.x, q01.y), w); w = cmul(w, stp);
        float2 r1 = cmul(make_float2(q01.z, q01.w), w); w = cmul(w, stp);
        float2 r2 = cmul(make_float2(q23.x, q23.y), w); w = cmul(w, stp);
        float2 r3 = cmul(make_float2(q23.z, q23.w), w);
        union { h8 v8; h2 v2[4]; } U;
        U.v2[0] = f2h(r0); U.v2[1] = f2h(r1); U.v2[2] = f2h(r2); U.v2[3] = f2h(r3);
        *((h8*)(buf + ((rbase + rl) * N2 + pp0))) = U.v8;
    }
}

// ---------------------------------------------------------------------------
// Inverse column FFT (512-pt DIT, brev load) over k1, scale, keep n1<256.
// ---------------------------------------------------------------------------
__global__ __launch_bounds__(512, 4) void inv_cols(
    const h2* __restrict__ src, float* __restrict__ out)
{
    __shared__ float4 s4[N1 * 16 / 2];            // 64 KB
    float2* s = (float2*)s4;
    const int tile = blockIdx.x, row = blockIdx.y, tid = threadIdx.x;
    const int n2base = tile * 16;
    const h2* srow = src + (size_t)row * N_FFT;
    const int cp = tid & 7, r8 = tid >> 3;        // r8 in [0,64)

#pragma unroll
    for (int i = 0; i < 8; i++) {
        int k1 = r8 + 64 * i;
        h4 v = *((const h4*)(srow + (size_t)k1 * N2 + n2base + 2 * cp));
        int p = brev9(k1);
        s4[p * 8 + cp] = make_float4((float)v.x, (float)v.y, (float)v.z, (float)v.w);
    }
    __syncthreads();

    const int c = tid & 15, r = tid >> 4;         // r in [0,32)

    // register octets: h=1 then fused (2,4), inverse constants
    const float2 w1c = make_float2(0.f, 1.f);     // conj(W_4^1) = i
    const float2 w2c = make_float2(R2_F, R2_F);   // conj(W_8^1)
    const float2 one = make_float2(1.f, 0.f);
#pragma unroll
    for (int o = 0; o < 2; o++) {
        int base = 8 * (r + 32 * o);
        float2 v[8];
#pragma unroll
        for (int m = 0; m < 8; m++) v[m] = s[(base + m) * 16 + c];
#pragma unroll
        for (int m = 0; m < 8; m += 2) {
            float2 a = v[m], b = v[m + 1];
            v[m] = cadd(a, b); v[m + 1] = csub(a, b);
        }
        dit4i(v[0], v[2], v[4], v[6], one, one);
        dit4i(v[1], v[3], v[5], v[7], w1c, w2c);
#pragma unroll
        for (int m = 0; m < 8; m++) s[(base + m) * 16 + c] = v[m];
    }
    __syncthreads();

    // fused (8,16): j = r&7 invariant
    {
        float2 w2 = expif((float)(r & 7) * (PI_F / 16.f));
        float2 w1 = csq(w2);
#pragma unroll
        for (int qq = 0; qq < 4; qq++) {
            int g = (r >> 3) + 4 * qq;
            int p0 = g * 32 + (r & 7);
            float2 a0 = s[p0*16+c], a1 = s[(p0+8)*16+c], a2 = s[(p0+16)*16+c], a3 = s[(p0+24)*16+c];
            dit4i(a0, a1, a2, a3, w1, w2);
            s[p0*16+c] = a0; s[(p0+8)*16+c] = a1; s[(p0+16)*16+c] = a2; s[(p0+24)*16+c] = a3;
        }
    }
    __syncthreads();
    // fused (32,64): j = r invariant
    {
        float2 w2 = expif((float)r * (PI_F / 64.f));
        float2 w1 = csq(w2);
#pragma unroll
        for (int qq = 0; qq < 4; qq++) {
            int p0 = qq * 128 + r;
            float2 a0 = s[p0*16+c], a1 = s[(p0+32)*16+c], a2 = s[(p0+64)*16+c], a3 = s[(p0+96)*16+c];
            dit4i(a0, a1, a2, a3, w1, w2);
            s[p0*16+c] = a0; s[(p0+32)*16+c] = a1; s[(p0+64)*16+c] = a2; s[(p0+96)*16+c] = a3;
        }
    }
    __syncthreads();
    // fused (128,256): chained, step = e^{+i pi/8}
    {
        float2 w2 = expif((float)r * (PI_F / 256.f));
        const float2 stp = make_float2(0.92387953251f, 0.38268343236f);
#pragma unroll
        for (int qq = 0; qq < 4; qq++) {
            int j = r + 32 * qq;
            float2 w1 = csq(w2);
            float2 a0 = s[j*16+c], a1 = s[(j+128)*16+c], a2 = s[(j+256)*16+c], a3 = s[(j+384)*16+c];
            dit4i(a0, a1, a2, a3, w1, w2);
            s[j*16+c] = a0; s[(j+128)*16+c] = a1; s[(j+256)*16+c] = a2; s[(j+384)*16+c] = a3;
            w2 = cmul(w2, stp);
        }
    }
    __syncthreads();

    const float scale = 1.0f / (float)N_FFT;
    float* out0 = out + (size_t)(2 * row) * T_LEN;
    float* out1 = out + (size_t)(2 * row + 1) * T_LEN;
#pragma unroll
    for (int i = 0; i < 4; i++) {
        int p = r8 + 64 * i;                      // p < 256
        float4 q = s4[p * 8 + cp];
        int n = p * N2 + n2base + 2 * cp;
        *(float2*)(out0 + n) = make_float2(q.x * scale, q.z * scale);
        *(float2*)(out1 + n) = make_float2(q.y * scale, q.w * scale);
    }
}

extern "C" void kernel_launch(void* const* d_in, const int* in_sizes, int n_in,
                              void* d_out, int out_size, void* d_ws, size_t ws_size,
                              hipStream_t stream) {
    const float* x    = (const float*)d_in[0];
    const float* filt = (const float*)d_in[1];
    float* out = (float*)d_out;

    h2* buf = (h2*)d_ws;                                                        // 67 MB
    float2* G = (float2*)((char*)d_ws + (size_t)CB * N_FFT * sizeof(h2));       // 1 MB

    fwd_cols<false><<<dim3(16, 1), 512, 0, stream>>>(filt, nullptr, 0LL, (void*)G);
    fwd_rows_g<<<N1 / 8, 256, 0, stream>>>(G);
    fwd_cols<true><<<dim3(16, CB), 512, 0, stream>>>(x, x + T_LEN, (long long)(2 * T_LEN), (void*)buf);
    mid_rows<<<(CB * N1) / 8, 512, 0, stream>>>(buf, G);
    inv_cols<<<dim3(16, CB), 512, 0, stream>>>(buf, out);
}